// Round 1
// baseline (2750.916 us; speedup 1.0000x reference)
//
#include <hip/hip_runtime.h>
#include <math.h>

#define N_NODES 8000
#define N_EDGES 24000
#define NB      256
#define ATOM    133
#define BOND    14
#define HDIM    256
#define HEADS   8
#define NLAYERS 5
#define NEG     0.2f
#define LN_EPS  1e-5f
#define EA      (N_EDGES + N_NODES)
#define HH      (HEADS * HDIM)   // 2048

// ---------------- block reductions ----------------
__device__ __forceinline__ float block_reduce_sum(float v, float* red) {
  int t = threadIdx.x;
  red[t] = v; __syncthreads();
  for (int s = blockDim.x >> 1; s > 0; s >>= 1) {
    if (t < s) red[t] += red[t + s];
    __syncthreads();
  }
  float r = red[0]; __syncthreads();
  return r;
}
__device__ __forceinline__ float block_reduce_max(float v, float* red) {
  int t = threadIdx.x;
  red[t] = v; __syncthreads();
  for (int s = blockDim.x >> 1; s > 0; s >>= 1) {
    if (t < s) red[t] = fmaxf(red[t], red[t + s]);
    __syncthreads();
  }
  float r = red[0]; __syncthreads();
  return r;
}

// ---------------- CSR setup ----------------
__global__ void k_deg(const int* __restrict__ dst, int* __restrict__ deg) {
  int e = blockIdx.x * blockDim.x + threadIdx.x;
  if (e < N_EDGES) atomicAdd(&deg[dst[e]], 1);
}

// single-block exclusive scan (n up to a few thousand); offs has n+1 entries
__global__ void k_scan(const int* __restrict__ cnt, int* __restrict__ offs, int n) {
  __shared__ int sh[256];
  __shared__ int carry_s;
  int t = threadIdx.x;
  if (t == 0) carry_s = 0;
  __syncthreads();
  for (int base = 0; base < n; base += 256) {
    int i = base + t;
    int v = (i < n) ? cnt[i] : 0;
    sh[t] = v;
    __syncthreads();
    for (int off = 1; off < 256; off <<= 1) {
      int tmp = (t >= off) ? sh[t - off] : 0;
      __syncthreads();
      sh[t] += tmp;
      __syncthreads();
    }
    int carry = carry_s;
    if (i < n) offs[i] = carry + sh[t] - v;
    __syncthreads();
    if (t == 255) carry_s = carry + sh[255];
    __syncthreads();
  }
  if (t == 0) offs[n] = carry_s;
}

__global__ void k_fill(const int* __restrict__ dst, const int* __restrict__ row_start,
                       int* __restrict__ cursor, int* __restrict__ csr_eid) {
  int e = blockIdx.x * blockDim.x + threadIdx.x;
  if (e < N_EDGES) {
    int d = dst[e];
    int pos = atomicAdd(&cursor[d], 1);
    csr_eid[row_start[d] + pos] = e;
  }
}

__global__ void k_loop_attr(const float* __restrict__ edge_attr, const int* __restrict__ row_start,
                            const int* __restrict__ csr_eid, float* __restrict__ loop_attr) {
  int t = blockIdx.x * blockDim.x + threadIdx.x;
  if (t >= N_NODES * BOND) return;
  int i = t / BOND, k = t % BOND;
  int beg = row_start[i], end = row_start[i + 1];
  float s = 0.f;
  for (int p = beg; p < end; p++) s += edge_attr[(size_t)csr_eid[p] * BOND + k];
  int degv = end - beg;
  loop_attr[(size_t)i * BOND + k] = s / fmaxf((float)degv, 1.f);
}

// ---------------- embedding: Linear -> LN -> ReLU ----------------
__global__ __launch_bounds__(256) void k_embed(const float* __restrict__ x, const float* __restrict__ W,
                                               const float* __restrict__ b, const float* __restrict__ g,
                                               const float* __restrict__ beta, float* __restrict__ h) {
  __shared__ float xs[ATOM];
  __shared__ float red[256];
  int i = blockIdx.x, j = threadIdx.x;
  if (j < ATOM) xs[j] = x[(size_t)i * ATOM + j];
  __syncthreads();
  float acc = b[j];
  for (int k = 0; k < ATOM; k++) acc += xs[k] * W[(size_t)k * HDIM + j];
  float mean = block_reduce_sum(acc, red) * (1.f / HDIM);
  float diff = acc - mean;
  float var = block_reduce_sum(diff * diff, red) * (1.f / HDIM);
  float vn = diff * rsqrtf(var + LN_EPS) * g[j] + beta[j];
  h[(size_t)i * HDIM + j] = fmaxf(vn, 0.f);
}

// ---------------- fp32 tiled GEMM: C[M,Nn] = A[M,K] @ B[K,Nn] ----------------
// M%64==0, Nn%64==0, K%16==0 required.
#define BM 64
#define BN 64
#define BK 16
__global__ __launch_bounds__(256) void k_gemm(const float* __restrict__ A, const float* __restrict__ Bm,
                                              float* __restrict__ C, int M, int Nn, int K) {
  __shared__ float As[BK][BM];
  __shared__ float Bs[BK][BN];
  int tid = threadIdx.x;
  int bm = blockIdx.y * BM, bn = blockIdx.x * BN;
  int ty = tid / 16, tx = tid % 16;
  int arow = tid >> 2, acol = (tid & 3) * 4;
  int brow = tid >> 4, bcol = (tid & 15) * 4;
  float acc[4][4] = {};
  for (int k0 = 0; k0 < K; k0 += BK) {
    float4 av = *(const float4*)&A[(size_t)(bm + arow) * K + k0 + acol];
    float4 bv = *(const float4*)&Bm[(size_t)(k0 + brow) * Nn + bn + bcol];
    __syncthreads();
    As[acol + 0][arow] = av.x; As[acol + 1][arow] = av.y;
    As[acol + 2][arow] = av.z; As[acol + 3][arow] = av.w;
    *(float4*)&Bs[brow][bcol] = bv;
    __syncthreads();
#pragma unroll
    for (int kk = 0; kk < BK; kk++) {
      float a0 = As[kk][ty * 4 + 0], a1 = As[kk][ty * 4 + 1];
      float a2 = As[kk][ty * 4 + 2], a3 = As[kk][ty * 4 + 3];
      float b0 = Bs[kk][tx * 4 + 0], b1 = Bs[kk][tx * 4 + 1];
      float b2 = Bs[kk][tx * 4 + 2], b3 = Bs[kk][tx * 4 + 3];
      acc[0][0] += a0 * b0; acc[0][1] += a0 * b1; acc[0][2] += a0 * b2; acc[0][3] += a0 * b3;
      acc[1][0] += a1 * b0; acc[1][1] += a1 * b1; acc[1][2] += a1 * b2; acc[1][3] += a1 * b3;
      acc[2][0] += a2 * b0; acc[2][1] += a2 * b1; acc[2][2] += a2 * b2; acc[2][3] += a2 * b3;
      acc[3][0] += a3 * b0; acc[3][1] += a3 * b1; acc[3][2] += a3 * b2; acc[3][3] += a3 * b3;
    }
  }
#pragma unroll
  for (int i = 0; i < 4; i++) {
    float4 v = make_float4(acc[i][0], acc[i][1], acc[i][2], acc[i][3]);
    *(float4*)&C[(size_t)(bm + ty * 4 + i) * Nn + bn + tx * 4] = v;
  }
}

// ---------------- edge attention scores ----------------
// one wave per (edge, head). We/att pointers are pre-offset per layer.
__global__ __launch_bounds__(256) void k_score(const float* __restrict__ xl, const float* __restrict__ xr,
                                               const float* __restrict__ edge_attr, const float* __restrict__ loop_attr,
                                               const float* __restrict__ We, const float* __restrict__ att,
                                               const int* __restrict__ src, const int* __restrict__ dst,
                                               float* __restrict__ score) {
  int w = blockIdx.x * 4 + (threadIdx.x >> 6);
  int lane = threadIdx.x & 63;
  int e = w >> 3, h = w & 7;
  if (e >= EA) return;
  int s, d;
  const float* ea;
  if (e < N_EDGES) { s = src[e]; d = dst[e]; ea = edge_attr + (size_t)e * BOND; }
  else             { s = d = e - N_EDGES;    ea = loop_attr + (size_t)(e - N_EDGES) * BOND; }
  float eav[BOND];
#pragma unroll
  for (int k = 0; k < BOND; k++) eav[k] = ea[k];
  const float* wp  = We + (size_t)h * HDIM;
  const float* xlp = xl + (size_t)s * HH + h * HDIM;
  const float* xrp = xr + (size_t)d * HH + h * HDIM;
  const float* ap  = att + h * HDIM;
  float acc = 0.f;
#pragma unroll
  for (int j = 0; j < 4; j++) {
    int dd = lane + 64 * j;
    float ee = 0.f;
#pragma unroll
    for (int k = 0; k < BOND; k++) ee += eav[k] * wp[(size_t)k * HH + dd];
    float f = xlp[dd] + xrp[dd] + ee;
    f = f > 0.f ? f : NEG * f;
    acc += f * ap[dd];
  }
  for (int off = 32; off > 0; off >>= 1) acc += __shfl_down(acc, off);
  if (lane == 0) score[(size_t)e * HEADS + h] = acc;
}

// ---------------- scatter softmax over incoming edges ----------------
__global__ void k_softmax(const float* __restrict__ score, const int* __restrict__ row_start,
                          const int* __restrict__ csr_eid, float* __restrict__ alpha) {
  int t = blockIdx.x * blockDim.x + threadIdx.x;
  if (t >= N_NODES * HEADS) return;
  int i = t >> 3, h = t & 7;
  int beg = row_start[i], end = row_start[i + 1];
  int eself = N_EDGES + i;
  float m = score[(size_t)eself * HEADS + h];
  for (int p = beg; p < end; p++) m = fmaxf(m, score[(size_t)csr_eid[p] * HEADS + h]);
  float ssum = expf(score[(size_t)eself * HEADS + h] - m);
  for (int p = beg; p < end; p++) ssum += expf(score[(size_t)csr_eid[p] * HEADS + h] - m);
  float inv = 1.f / ssum;
  alpha[(size_t)eself * HEADS + h] = expf(score[(size_t)eself * HEADS + h] - m) * inv;
  for (int p = beg; p < end; p++) {
    int e = csr_eid[p];
    alpha[(size_t)e * HEADS + h] = expf(score[(size_t)e * HEADS + h] - m) * inv;
  }
}

// ---------------- aggregate + head-mean + bias + residual + LN ----------------
__global__ __launch_bounds__(256) void k_agg(const float* __restrict__ xl, const float* __restrict__ alpha,
                                             const int* __restrict__ row_start, const int* __restrict__ csr_eid,
                                             const int* __restrict__ src, const float* __restrict__ bias,
                                             const float* __restrict__ lng, const float* __restrict__ lnb,
                                             float* __restrict__ h) {
  __shared__ float red[256];
  int i = blockIdx.x, d = threadIdx.x;
  int beg = row_start[i], end = row_start[i + 1];
  float acc = 0.f;
  for (int hh = 0; hh < HEADS; hh++) {
    float s = alpha[(size_t)(N_EDGES + i) * HEADS + hh] * xl[(size_t)i * HH + hh * HDIM + d];
    for (int p = beg; p < end; p++) {
      int e = csr_eid[p];
      int sn = src[e];
      s += alpha[(size_t)e * HEADS + hh] * xl[(size_t)sn * HH + hh * HDIM + d];
    }
    acc += s;
  }
  float v = acc * (1.f / HEADS) + bias[d] + h[(size_t)i * HDIM + d];
  float mean = block_reduce_sum(v, red) * (1.f / HDIM);
  float diff = v - mean;
  float var = block_reduce_sum(diff * diff, red) * (1.f / HDIM);
  h[(size_t)i * HDIM + d] = diff * rsqrtf(var + LN_EPS) * lng[d] + lnb[d];
}

// ---------------- readout: gate MLP ----------------
__global__ __launch_bounds__(128) void k_gate(const float* __restrict__ h, const float* __restrict__ g1W,
                                              const float* __restrict__ g1b, const float* __restrict__ g2W,
                                              const float* __restrict__ g2b, float* __restrict__ gate) {
  __shared__ float red[128];
  int i = blockIdx.x, j = threadIdx.x;
  const float* hp = h + (size_t)i * HDIM;
  float acc = g1b[j];
  for (int k = 0; k < HDIM; k++) acc += hp[k] * g1W[(size_t)k * (HDIM / 2) + j];
  float r = fmaxf(acc, 0.f) * g2W[j];
  float tot = block_reduce_sum(r, red);
  if (j == 0) gate[i] = tot + g2b[0];
}

__global__ void k_gcount(const int* __restrict__ batch, int* __restrict__ gcnt) {
  int i = blockIdx.x * blockDim.x + threadIdx.x;
  if (i < N_NODES) atomicAdd(&gcnt[batch[i]], 1);
}

// ---------------- per-graph softmax-weighted sum ----------------
__global__ __launch_bounds__(256) void k_readout(const float* __restrict__ h, const float* __restrict__ gate,
                                                 const int* __restrict__ goff, float* __restrict__ out) {
  __shared__ float red[256];
  int b = blockIdx.x, t = threadIdx.x;
  int beg = goff[b], end = goff[b + 1];
  if (end <= beg) { out[(size_t)b * HDIM + t] = 0.f; return; }
  float lm = -3.4e38f;
  for (int i = beg + t; i < end; i += 256) lm = fmaxf(lm, gate[i]);
  float m = block_reduce_max(lm, red);
  float ls = 0.f;
  for (int i = beg + t; i < end; i += 256) ls += expf(gate[i] - m);
  float s = block_reduce_sum(ls, red);
  float inv = 1.f / fmaxf(s, 1e-16f);
  float acc = 0.f;
  for (int i = beg; i < end; i++) acc += expf(gate[i] - m) * h[(size_t)i * HDIM + t];
  out[(size_t)b * HDIM + t] = acc * inv;
}

// ---------------- launch ----------------
extern "C" void kernel_launch(void* const* d_in, const int* in_sizes, int n_in,
                              void* d_out, int out_size, void* d_ws, size_t ws_size,
                              hipStream_t stream) {
  const float* x         = (const float*)d_in[0];
  const float* edge_attr = (const float*)d_in[1];
  const float* emb_W     = (const float*)d_in[2];
  const float* emb_b     = (const float*)d_in[3];
  const float* emb_g     = (const float*)d_in[4];
  const float* emb_beta  = (const float*)d_in[5];
  const float* Wl        = (const float*)d_in[6];
  const float* Wr        = (const float*)d_in[7];
  const float* We        = (const float*)d_in[8];
  const float* att       = (const float*)d_in[9];
  const float* bias      = (const float*)d_in[10];
  const float* ln_g      = (const float*)d_in[11];
  const float* ln_b      = (const float*)d_in[12];
  const float* g1W       = (const float*)d_in[13];
  const float* g1b       = (const float*)d_in[14];
  const float* g2W       = (const float*)d_in[15];
  const float* g2b       = (const float*)d_in[16];
  const int*   edge_index= (const int*)d_in[17];
  const int*   batch     = (const int*)d_in[18];
  float* out = (float*)d_out;

  const int* src = edge_index;
  const int* dst = edge_index + N_EDGES;

  char* p = (char*)d_ws;
  auto alloc = [&](size_t bytes) -> void* {
    void* r = (void*)p;
    p += (bytes + 255) & ~(size_t)255;
    return r;
  };
  int*   deg       = (int*)alloc((size_t)N_NODES * 4);
  int*   row_start = (int*)alloc((size_t)(N_NODES + 1) * 4);
  int*   cursor    = (int*)alloc((size_t)N_NODES * 4);
  int*   csr_eid   = (int*)alloc((size_t)N_EDGES * 4);
  float* loop_attr = (float*)alloc((size_t)N_NODES * BOND * 4);
  float* h         = (float*)alloc((size_t)N_NODES * HDIM * 4);
  float* xl        = (float*)alloc((size_t)N_NODES * HH * 4);
  float* xr        = (float*)alloc((size_t)N_NODES * HH * 4);
  float* score     = (float*)alloc((size_t)EA * HEADS * 4);
  float* alpha     = (float*)alloc((size_t)EA * HEADS * 4);
  float* gate      = (float*)alloc((size_t)N_NODES * 4);
  int*   gcnt      = (int*)alloc((size_t)NB * 4);
  int*   goff      = (int*)alloc((size_t)(NB + 1) * 4);

  hipMemsetAsync(deg, 0, (size_t)N_NODES * 4, stream);
  hipMemsetAsync(cursor, 0, (size_t)N_NODES * 4, stream);
  hipMemsetAsync(gcnt, 0, (size_t)NB * 4, stream);

  k_deg<<<(N_EDGES + 255) / 256, 256, 0, stream>>>(dst, deg);
  k_scan<<<1, 256, 0, stream>>>(deg, row_start, N_NODES);
  k_fill<<<(N_EDGES + 255) / 256, 256, 0, stream>>>(dst, row_start, cursor, csr_eid);
  k_loop_attr<<<(N_NODES * BOND + 255) / 256, 256, 0, stream>>>(edge_attr, row_start, csr_eid, loop_attr);
  k_embed<<<N_NODES, 256, 0, stream>>>(x, emb_W, emb_b, emb_g, emb_beta, h);

  dim3 ggrid(HH / BN, N_NODES / BM);  // (32, 125)
  for (int l = 0; l < NLAYERS; l++) {
    const float* Wl_l = Wl + (size_t)l * HDIM * HH;
    const float* Wr_l = Wr + (size_t)l * HDIM * HH;
    const float* We_l = We + (size_t)l * BOND * HH;
    const float* att_l = att + (size_t)l * HEADS * HDIM;
    k_gemm<<<ggrid, 256, 0, stream>>>(h, Wl_l, xl, N_NODES, HH, HDIM);
    k_gemm<<<ggrid, 256, 0, stream>>>(h, Wr_l, xr, N_NODES, HH, HDIM);
    k_score<<<(EA * HEADS + 3) / 4, 256, 0, stream>>>(xl, xr, edge_attr, loop_attr, We_l, att_l, src, dst, score);
    k_softmax<<<(N_NODES * HEADS + 255) / 256, 256, 0, stream>>>(score, row_start, csr_eid, alpha);
    k_agg<<<N_NODES, 256, 0, stream>>>(xl, alpha, row_start, csr_eid, src,
                                       bias + (size_t)l * HDIM, ln_g + (size_t)l * HDIM,
                                       ln_b + (size_t)l * HDIM, h);
  }

  k_gate<<<N_NODES, 128, 0, stream>>>(h, g1W, g1b, g2W, g2b, gate);
  k_gcount<<<(N_NODES + 255) / 256, 256, 0, stream>>>(batch, gcnt);
  k_scan<<<1, 256, 0, stream>>>(gcnt, goff, NB);
  k_readout<<<NB, 256, 0, stream>>>(h, gate, goff, out);
}

// Round 2
// 1996.000 us; speedup vs baseline: 1.3782x; 1.3782x over previous
//
#include <hip/hip_runtime.h>
#include <math.h>

#define N_NODES 8000
#define N_EDGES 24000
#define NB      256
#define ATOM    133
#define BOND    14
#define HDIM    256
#define HEADS   8
#define NLAYERS 5
#define NEG     0.2f
#define LN_EPS  1e-5f
#define HH      (HEADS * HDIM)   // 2048
#define MPAD    8064             // 63*128, padded rows for GEMM

typedef __attribute__((ext_vector_type(8))) short short8;
typedef __attribute__((ext_vector_type(4))) float floatx4;

// ---------------- bf16 helpers (RNE) ----------------
__device__ __forceinline__ unsigned short f2bf(float f) {
  unsigned u = __float_as_uint(f);
  unsigned r = (u + 0x7fff + ((u >> 16) & 1)) >> 16;
  return (unsigned short)r;
}
__device__ __forceinline__ float bf2f(unsigned short h) {
  return __uint_as_float(((unsigned)h) << 16);
}

// ---------------- async global->LDS 16B ----------------
__device__ __forceinline__ void load_lds16(const void* g, void* l) {
  __builtin_amdgcn_global_load_lds((const __attribute__((address_space(1))) unsigned int*)g,
                                   (__attribute__((address_space(3))) unsigned int*)l,
                                   16, 0, 0);
}

// ---------------- block reductions ----------------
__device__ __forceinline__ float block_reduce_sum(float v, float* red) {
  int t = threadIdx.x;
  red[t] = v; __syncthreads();
  for (int s = blockDim.x >> 1; s > 0; s >>= 1) {
    if (t < s) red[t] += red[t + s];
    __syncthreads();
  }
  float r = red[0]; __syncthreads();
  return r;
}
__device__ __forceinline__ float block_reduce_max(float v, float* red) {
  int t = threadIdx.x;
  red[t] = v; __syncthreads();
  for (int s = blockDim.x >> 1; s > 0; s >>= 1) {
    if (t < s) red[t] = fmaxf(red[t], red[t + s]);
    __syncthreads();
  }
  float r = red[0]; __syncthreads();
  return r;
}

// ---------------- CSR setup ----------------
__global__ void k_deg(const int* __restrict__ dst, int* __restrict__ deg) {
  int e = blockIdx.x * blockDim.x + threadIdx.x;
  if (e < N_EDGES) atomicAdd(&deg[dst[e]], 1);
}

__global__ void k_scan(const int* __restrict__ cnt, int* __restrict__ offs, int n) {
  __shared__ int sh[256];
  __shared__ int carry_s;
  int t = threadIdx.x;
  if (t == 0) carry_s = 0;
  __syncthreads();
  for (int base = 0; base < n; base += 256) {
    int i = base + t;
    int v = (i < n) ? cnt[i] : 0;
    sh[t] = v;
    __syncthreads();
    for (int off = 1; off < 256; off <<= 1) {
      int tmp = (t >= off) ? sh[t - off] : 0;
      __syncthreads();
      sh[t] += tmp;
      __syncthreads();
    }
    int carry = carry_s;
    if (i < n) offs[i] = carry + sh[t] - v;
    __syncthreads();
    if (t == 255) carry_s = carry + sh[255];
    __syncthreads();
  }
  if (t == 0) offs[n] = carry_s;
}

__global__ void k_fill(const int* __restrict__ dst, const int* __restrict__ row_start,
                       int* __restrict__ cursor, int* __restrict__ csr_eid) {
  int e = blockIdx.x * blockDim.x + threadIdx.x;
  if (e < N_EDGES) {
    int d = dst[e];
    int pos = atomicAdd(&cursor[d], 1);
    csr_eid[row_start[d] + pos] = e;
  }
}

__global__ void k_loop_attr(const float* __restrict__ edge_attr, const int* __restrict__ row_start,
                            const int* __restrict__ csr_eid, float* __restrict__ loop_attr) {
  int t = blockIdx.x * blockDim.x + threadIdx.x;
  if (t >= N_NODES * BOND) return;
  int i = t / BOND, k = t % BOND;
  int beg = row_start[i], end = row_start[i + 1];
  float s = 0.f;
  for (int p = beg; p < end; p++) s += edge_attr[(size_t)csr_eid[p] * BOND + k];
  int degv = end - beg;
  loop_attr[(size_t)i * BOND + k] = s / fmaxf((float)degv, 1.f);
}

// ---------------- build Bt: [L][4096][512] bf16 = [Bh | Bl] of [Wl|Wr]^T ----------------
__global__ __launch_bounds__(256) void k_build_bt(const float* __restrict__ Wl,
                                                  const float* __restrict__ Wr,
                                                  unsigned short* __restrict__ Bt) {
  int l = blockIdx.x >> 12;          // /4096
  int n = blockIdx.x & 4095;
  int k = threadIdx.x;               // 0..255
  const float* Wsrc = (n < HH) ? Wl : Wr;
  int nn = (n < HH) ? n : n - HH;
  float w = Wsrc[(size_t)l * HDIM * HH + (size_t)k * HH + nn];
  unsigned short hi = f2bf(w);
  unsigned short lo = f2bf(w - bf2f(hi));
  unsigned short* row = Bt + ((size_t)l * 4096 + n) * 512;
  row[k] = hi;
  row[256 + k] = lo;
}

// ---------------- embedding: Linear -> LN -> ReLU, writes h + Abuf(hi|lo) ----------------
__global__ __launch_bounds__(256) void k_embed(const float* __restrict__ x, const float* __restrict__ W,
                                               const float* __restrict__ b, const float* __restrict__ g,
                                               const float* __restrict__ beta, float* __restrict__ h,
                                               unsigned short* __restrict__ Abuf) {
  __shared__ float xs[ATOM];
  __shared__ float red[256];
  int i = blockIdx.x, j = threadIdx.x;
  if (j < ATOM) xs[j] = x[(size_t)i * ATOM + j];
  __syncthreads();
  float acc = b[j];
  for (int k = 0; k < ATOM; k++) acc += xs[k] * W[(size_t)k * HDIM + j];
  float mean = block_reduce_sum(acc, red) * (1.f / HDIM);
  float diff = acc - mean;
  float var = block_reduce_sum(diff * diff, red) * (1.f / HDIM);
  float vn = diff * rsqrtf(var + LN_EPS) * g[j] + beta[j];
  float r = fmaxf(vn, 0.f);
  h[(size_t)i * HDIM + j] = r;
  unsigned short hi = f2bf(r);
  Abuf[(size_t)i * 512 + j] = hi;
  Abuf[(size_t)i * 512 + 256 + j] = f2bf(r - bf2f(hi));
}

// ---------------- MFMA GEMM: C[8000x4096] = A'[Mx768] @ B'[768x4096] ----------------
// A' logical K-blocks: [Ah | Al | Ah] from Abuf[M][512]=[Ah|Al]
// B' logical K-blocks: [Bh | Bh | Bl] from Bt[4096][512]=[Bh|Bl] (n-major, k-minor)
__global__ __launch_bounds__(256) void k_gemm_mfma(const unsigned short* __restrict__ A,
                                                   const unsigned short* __restrict__ Bt,
                                                   float* __restrict__ C) {
  __shared__ unsigned short As[128 * 32];
  __shared__ unsigned short Bs[128 * 32];
  const int tid = threadIdx.x;
  const int wave = tid >> 6, lane = tid & 63;
  const int bm = blockIdx.y * 128, bn = blockIdx.x * 128;
  const int wm = (wave >> 1) * 64, wn = (wave & 1) * 64;

  const int c0 = tid, c1 = tid + 256;
  const int ar0 = c0 >> 2, ap0 = (c0 & 3) * 8;
  const int ar1 = c1 >> 2, ap1 = (c1 & 3) * 8;
  const unsigned short* agA0 = A + (size_t)(bm + ar0) * 512 + ap0;
  const unsigned short* agA1 = A + (size_t)(bm + ar1) * 512 + ap1;
  const unsigned short* agB0 = Bt + (size_t)(bn + ar0) * 512 + ap0;
  const unsigned short* agB1 = Bt + (size_t)(bn + ar1) * 512 + ap1;
  unsigned short* alA0 = As + c0 * 8;
  unsigned short* alA1 = As + c1 * 8;
  unsigned short* alB0 = Bs + c0 * 8;
  unsigned short* alB1 = Bs + c1 * 8;

  floatx4 acc[4][4] = {};
  const int mrow = lane & 15;
  const int kq = (lane >> 4) * 8;

  for (int k0 = 0; k0 < 768; k0 += 32) {
    int aoff = (k0 < 512) ? k0 : k0 - 512;   // Ah, Al, Ah
    int boff = (k0 < 256) ? k0 : k0 - 256;   // Bh, Bh, Bl
    load_lds16(agA0 + aoff, alA0);
    load_lds16(agA1 + aoff, alA1);
    load_lds16(agB0 + boff, alB0);
    load_lds16(agB1 + boff, alB1);
    __syncthreads();  // drains vmcnt -> LDS populated, all waves ready
    short8 af[4], bfr[4];
#pragma unroll
    for (int mi = 0; mi < 4; mi++)
      af[mi] = *(const short8*)&As[(wm + mi * 16 + mrow) * 32 + kq];
#pragma unroll
    for (int ni = 0; ni < 4; ni++)
      bfr[ni] = *(const short8*)&Bs[(wn + ni * 16 + mrow) * 32 + kq];
#pragma unroll
    for (int mi = 0; mi < 4; mi++)
#pragma unroll
      for (int ni = 0; ni < 4; ni++)
        acc[mi][ni] = __builtin_amdgcn_mfma_f32_16x16x32_bf16(af[mi], bfr[ni], acc[mi][ni], 0, 0, 0);
    __syncthreads();  // all waves done reading before next stage overwrites
  }
  const int crow0 = bm + wm + (lane >> 4) * 4;
  const int ccol0 = bn + wn + (lane & 15);
#pragma unroll
  for (int mi = 0; mi < 4; mi++) {
#pragma unroll
    for (int ni = 0; ni < 4; ni++) {
#pragma unroll
      for (int r = 0; r < 4; r++) {
        int row = crow0 + mi * 16 + r;
        if (row < N_NODES)
          C[(size_t)row * 4096 + ccol0 + ni * 16] = acc[mi][ni][r];
      }
    }
  }
}

// ---------------- fused attention: score + online softmax + aggregate ----------------
// grid (250, 8): block = (node-group of 32, head). One wave handles 8 nodes for one head.
// We head-slice lives in 56 VGPRs per lane. Results atomically accumulated into acc[node][d].
__device__ __forceinline__ float edge_score(float x0, float x1, float x2, float x3,
                                            float r0, float r1, float r2, float r3,
                                            const float eav[BOND], const float wreg[BOND][4],
                                            float a0, float a1, float a2, float a3) {
  float e0 = 0.f, e1 = 0.f, e2 = 0.f, e3 = 0.f;
#pragma unroll
  for (int k = 0; k < BOND; k++) {
    e0 += eav[k] * wreg[k][0]; e1 += eav[k] * wreg[k][1];
    e2 += eav[k] * wreg[k][2]; e3 += eav[k] * wreg[k][3];
  }
  float f0 = x0 + r0 + e0; f0 = f0 > 0.f ? f0 : NEG * f0;
  float f1 = x1 + r1 + e1; f1 = f1 > 0.f ? f1 : NEG * f1;
  float f2 = x2 + r2 + e2; f2 = f2 > 0.f ? f2 : NEG * f2;
  float f3 = x3 + r3 + e3; f3 = f3 > 0.f ? f3 : NEG * f3;
  float sp = f0 * a0 + f1 * a1 + f2 * a2 + f3 * a3;
#pragma unroll
  for (int off = 32; off > 0; off >>= 1) sp += __shfl_xor(sp, off);
  return sp;
}

__global__ __launch_bounds__(256) void k_attn(const float* __restrict__ xlr,
    const float* __restrict__ edge_attr, const float* __restrict__ loop_attr,
    const float* __restrict__ We, const float* __restrict__ att,
    const int* __restrict__ row_start, const int* __restrict__ csr_eid,
    const int* __restrict__ src, float* __restrict__ acc) {
  __shared__ float sWe[BOND * HDIM];
  const int hh = blockIdx.y;
  const int g  = blockIdx.x;
  const int tid = threadIdx.x, wave = tid >> 6, lane = tid & 63;
  for (int idx = tid; idx < BOND * HDIM; idx += 256) {
    int k = idx >> 8, d = idx & 255;
    sWe[idx] = We[(size_t)k * HH + hh * HDIM + d];
  }
  __syncthreads();
  float wreg[BOND][4];
#pragma unroll
  for (int k = 0; k < BOND; k++) {
    float4 t = *(const float4*)&sWe[k * HDIM + lane * 4];
    wreg[k][0] = t.x; wreg[k][1] = t.y; wreg[k][2] = t.z; wreg[k][3] = t.w;
  }
  float4 at4 = *(const float4*)&att[hh * HDIM + lane * 4];

  for (int ni = 0; ni < 8; ni++) {
    int i = (g * 4 + wave) * 8 + ni;
    int beg = row_start[i], end = row_start[i + 1];
    float4 xr4 = *(const float4*)&xlr[(size_t)i * 4096 + 2048 + hh * HDIM + lane * 4];
    float eav[BOND];
#pragma unroll
    for (int k = 0; k < BOND; k++) eav[k] = loop_attr[(size_t)i * BOND + k];
    float4 xl4 = *(const float4*)&xlr[(size_t)i * 4096 + hh * HDIM + lane * 4];
    float s = edge_score(xl4.x, xl4.y, xl4.z, xl4.w, xr4.x, xr4.y, xr4.z, xr4.w,
                         eav, wreg, at4.x, at4.y, at4.z, at4.w);
    float m = s, l = 1.f;
    float o0 = xl4.x, o1 = xl4.y, o2 = xl4.z, o3 = xl4.w;
    for (int p = beg; p < end; p++) {
      int e = csr_eid[p];
      int sn = src[e];
#pragma unroll
      for (int k = 0; k < BOND; k++) eav[k] = edge_attr[(size_t)e * BOND + k];
      float4 x4 = *(const float4*)&xlr[(size_t)sn * 4096 + hh * HDIM + lane * 4];
      float s2 = edge_score(x4.x, x4.y, x4.z, x4.w, xr4.x, xr4.y, xr4.z, xr4.w,
                            eav, wreg, at4.x, at4.y, at4.z, at4.w);
      float mn = fmaxf(m, s2);
      float ca = __expf(m - mn), cb = __expf(s2 - mn);
      o0 = o0 * ca + x4.x * cb;
      o1 = o1 * ca + x4.y * cb;
      o2 = o2 * ca + x4.z * cb;
      o3 = o3 * ca + x4.w * cb;
      l = l * ca + cb;
      m = mn;
    }
    float inv = 1.f / l;
    float* ap = &acc[(size_t)i * HDIM + lane * 4];
    atomicAdd(ap + 0, o0 * inv);
    atomicAdd(ap + 1, o1 * inv);
    atomicAdd(ap + 2, o2 * inv);
    atomicAdd(ap + 3, o3 * inv);
  }
}

// ---------------- head-mean + bias + residual + LN, writes h + Abuf ----------------
__global__ __launch_bounds__(256) void k_ln(const float* __restrict__ acc, const float* __restrict__ bias,
                                            const float* __restrict__ lng, const float* __restrict__ lnb,
                                            float* __restrict__ h, unsigned short* __restrict__ Abuf) {
  __shared__ float red[256];
  int i = blockIdx.x, d = threadIdx.x;
  float v = acc[(size_t)i * HDIM + d] * 0.125f + bias[d] + h[(size_t)i * HDIM + d];
  float mean = block_reduce_sum(v, red) * (1.f / HDIM);
  float diff = v - mean;
  float var = block_reduce_sum(diff * diff, red) * (1.f / HDIM);
  float r = diff * rsqrtf(var + LN_EPS) * lng[d] + lnb[d];
  h[(size_t)i * HDIM + d] = r;
  unsigned short hi = f2bf(r);
  Abuf[(size_t)i * 512 + d] = hi;
  Abuf[(size_t)i * 512 + 256 + d] = f2bf(r - bf2f(hi));
}

// ---------------- readout: gate MLP ----------------
__global__ __launch_bounds__(128) void k_gate(const float* __restrict__ h, const float* __restrict__ g1W,
                                              const float* __restrict__ g1b, const float* __restrict__ g2W,
                                              const float* __restrict__ g2b, float* __restrict__ gate) {
  __shared__ float red[128];
  int i = blockIdx.x, j = threadIdx.x;
  const float* hp = h + (size_t)i * HDIM;
  float acc = g1b[j];
  for (int k = 0; k < HDIM; k++) acc += hp[k] * g1W[(size_t)k * (HDIM / 2) + j];
  float r = fmaxf(acc, 0.f) * g2W[j];
  float tot = block_reduce_sum(r, red);
  if (j == 0) gate[i] = tot + g2b[0];
}

__global__ void k_gcount(const int* __restrict__ batch, int* __restrict__ gcnt) {
  int i = blockIdx.x * blockDim.x + threadIdx.x;
  if (i < N_NODES) atomicAdd(&gcnt[batch[i]], 1);
}

__global__ __launch_bounds__(256) void k_readout(const float* __restrict__ h, const float* __restrict__ gate,
                                                 const int* __restrict__ goff, float* __restrict__ out) {
  __shared__ float red[256];
  int b = blockIdx.x, t = threadIdx.x;
  int beg = goff[b], end = goff[b + 1];
  if (end <= beg) { out[(size_t)b * HDIM + t] = 0.f; return; }
  float lm = -3.4e38f;
  for (int i = beg + t; i < end; i += 256) lm = fmaxf(lm, gate[i]);
  float m = block_reduce_max(lm, red);
  float ls = 0.f;
  for (int i = beg + t; i < end; i += 256) ls += __expf(gate[i] - m);
  float s = block_reduce_sum(ls, red);
  float inv = 1.f / fmaxf(s, 1e-16f);
  float acc = 0.f;
  for (int i = beg; i < end; i++) acc += __expf(gate[i] - m) * h[(size_t)i * HDIM + t];
  out[(size_t)b * HDIM + t] = acc * inv;
}

// ---------------- launch ----------------
extern "C" void kernel_launch(void* const* d_in, const int* in_sizes, int n_in,
                              void* d_out, int out_size, void* d_ws, size_t ws_size,
                              hipStream_t stream) {
  const float* x         = (const float*)d_in[0];
  const float* edge_attr = (const float*)d_in[1];
  const float* emb_W     = (const float*)d_in[2];
  const float* emb_b     = (const float*)d_in[3];
  const float* emb_g     = (const float*)d_in[4];
  const float* emb_beta  = (const float*)d_in[5];
  const float* Wl        = (const float*)d_in[6];
  const float* Wr        = (const float*)d_in[7];
  const float* We        = (const float*)d_in[8];
  const float* att       = (const float*)d_in[9];
  const float* bias      = (const float*)d_in[10];
  const float* ln_g      = (const float*)d_in[11];
  const float* ln_b      = (const float*)d_in[12];
  const float* g1W       = (const float*)d_in[13];
  const float* g1b       = (const float*)d_in[14];
  const float* g2W       = (const float*)d_in[15];
  const float* g2b       = (const float*)d_in[16];
  const int*   edge_index= (const int*)d_in[17];
  const int*   batch     = (const int*)d_in[18];
  float* out = (float*)d_out;

  const int* src = edge_index;
  const int* dst = edge_index + N_EDGES;

  char* p = (char*)d_ws;
  auto alloc = [&](size_t bytes) -> void* {
    void* r = (void*)p;
    p += (bytes + 255) & ~(size_t)255;
    return r;
  };
  int*   deg       = (int*)alloc((size_t)N_NODES * 4);
  int*   row_start = (int*)alloc((size_t)(N_NODES + 1) * 4);
  int*   cursor    = (int*)alloc((size_t)N_NODES * 4);
  int*   csr_eid   = (int*)alloc((size_t)N_EDGES * 4);
  float* loop_attr = (float*)alloc((size_t)N_NODES * BOND * 4);
  float* h         = (float*)alloc((size_t)N_NODES * HDIM * 4);
  unsigned short* Abuf = (unsigned short*)alloc((size_t)MPAD * 512 * 2);
  unsigned short* Bt   = (unsigned short*)alloc((size_t)NLAYERS * 4096 * 512 * 2);
  float* xlr       = (float*)alloc((size_t)N_NODES * 4096 * 4);
  float* accb      = (float*)alloc((size_t)N_NODES * HDIM * 4);
  float* gate      = (float*)alloc((size_t)N_NODES * 4);
  int*   gcnt      = (int*)alloc((size_t)NB * 4);
  int*   goff      = (int*)alloc((size_t)(NB + 1) * 4);

  hipMemsetAsync(deg, 0, (size_t)N_NODES * 4, stream);
  hipMemsetAsync(cursor, 0, (size_t)N_NODES * 4, stream);
  hipMemsetAsync(gcnt, 0, (size_t)NB * 4, stream);

  k_deg<<<(N_EDGES + 255) / 256, 256, 0, stream>>>(dst, deg);
  k_scan<<<1, 256, 0, stream>>>(deg, row_start, N_NODES);
  k_fill<<<(N_EDGES + 255) / 256, 256, 0, stream>>>(dst, row_start, cursor, csr_eid);
  k_loop_attr<<<(N_NODES * BOND + 255) / 256, 256, 0, stream>>>(edge_attr, row_start, csr_eid, loop_attr);
  k_build_bt<<<NLAYERS * 4096, 256, 0, stream>>>(Wl, Wr, Bt);
  k_embed<<<N_NODES, 256, 0, stream>>>(x, emb_W, emb_b, emb_g, emb_beta, h, Abuf);

  dim3 ggrid(4096 / 128, MPAD / 128);  // (32, 63)
  for (int l = 0; l < NLAYERS; l++) {
    const unsigned short* Bt_l = Bt + (size_t)l * 4096 * 512;
    const float* We_l  = We + (size_t)l * BOND * HH;
    const float* att_l = att + (size_t)l * HEADS * HDIM;
    hipMemsetAsync(accb, 0, (size_t)N_NODES * HDIM * 4, stream);
    k_gemm_mfma<<<ggrid, 256, 0, stream>>>(Abuf, Bt_l, xlr);
    k_attn<<<dim3(250, HEADS), 256, 0, stream>>>(xlr, edge_attr, loop_attr, We_l, att_l,
                                                 row_start, csr_eid, src, accb);
    k_ln<<<N_NODES, 256, 0, stream>>>(accb, bias + (size_t)l * HDIM,
                                      ln_g + (size_t)l * HDIM, ln_b + (size_t)l * HDIM, h, Abuf);
  }

  k_gate<<<N_NODES, 128, 0, stream>>>(h, g1W, g1b, g2W, g2b, gate);
  k_gcount<<<(N_NODES + 255) / 256, 256, 0, stream>>>(batch, gcnt);
  k_scan<<<1, 256, 0, stream>>>(gcnt, goff, NB);
  k_readout<<<NB, 256, 0, stream>>>(h, gate, goff, out);
}

// Round 3
// 1204.426 us; speedup vs baseline: 2.2840x; 1.6572x over previous
//
#include <hip/hip_runtime.h>
#include <math.h>

#define N_NODES 8000
#define N_EDGES 24000
#define NB      256
#define ATOM    133
#define BOND    14
#define HDIM    256
#define HEADS   8
#define NLAYERS 5
#define NEG     0.2f
#define LN_EPS  1e-5f
#define HH      (HEADS * HDIM)   // 2048
#define MPAD    8064             // 63*128, padded rows for GEMM

typedef __attribute__((ext_vector_type(8))) short short8;
typedef __attribute__((ext_vector_type(4))) float floatx4;
typedef unsigned short ushort_t;

// ---------------- bf16 helpers (RNE) ----------------
__device__ __forceinline__ ushort_t f2bf(float f) {
  unsigned u = __float_as_uint(f);
  unsigned r = (u + 0x7fff + ((u >> 16) & 1)) >> 16;
  return (ushort_t)r;
}
__device__ __forceinline__ float bf2f(ushort_t h) {
  return __uint_as_float(((unsigned)h) << 16);
}
__device__ __forceinline__ float4 ldbf4(const ushort_t* p) {
  ushort4 u = *(const ushort4*)p;
  return make_float4(bf2f(u.x), bf2f(u.y), bf2f(u.z), bf2f(u.w));
}

// ---------------- async global->LDS 16B ----------------
__device__ __forceinline__ void load_lds16(const void* g, void* l) {
  __builtin_amdgcn_global_load_lds((const __attribute__((address_space(1))) unsigned int*)g,
                                   (__attribute__((address_space(3))) unsigned int*)l,
                                   16, 0, 0);
}

// ---------------- block reductions ----------------
__device__ __forceinline__ float block_reduce_sum(float v, float* red) {
  int t = threadIdx.x;
  red[t] = v; __syncthreads();
  for (int s = blockDim.x >> 1; s > 0; s >>= 1) {
    if (t < s) red[t] += red[t + s];
    __syncthreads();
  }
  float r = red[0]; __syncthreads();
  return r;
}
__device__ __forceinline__ float block_reduce_max(float v, float* red) {
  int t = threadIdx.x;
  red[t] = v; __syncthreads();
  for (int s = blockDim.x >> 1; s > 0; s >>= 1) {
    if (t < s) red[t] = fmaxf(red[t], red[t + s]);
    __syncthreads();
  }
  float r = red[0]; __syncthreads();
  return r;
}

// ---------------- CSR setup ----------------
__global__ void k_deg(const int* __restrict__ dst, int* __restrict__ deg) {
  int e = blockIdx.x * blockDim.x + threadIdx.x;
  if (e < N_EDGES) atomicAdd(&deg[dst[e]], 1);
}

__global__ void k_scan(const int* __restrict__ cnt, int* __restrict__ offs, int n) {
  __shared__ int sh[256];
  __shared__ int carry_s;
  int t = threadIdx.x;
  if (t == 0) carry_s = 0;
  __syncthreads();
  for (int base = 0; base < n; base += 256) {
    int i = base + t;
    int v = (i < n) ? cnt[i] : 0;
    sh[t] = v;
    __syncthreads();
    for (int off = 1; off < 256; off <<= 1) {
      int tmp = (t >= off) ? sh[t - off] : 0;
      __syncthreads();
      sh[t] += tmp;
      __syncthreads();
    }
    int carry = carry_s;
    if (i < n) offs[i] = carry + sh[t] - v;
    __syncthreads();
    if (t == 255) carry_s = carry + sh[255];
    __syncthreads();
  }
  if (t == 0) offs[n] = carry_s;
}

__global__ void k_fill(const int* __restrict__ dst, const int* __restrict__ row_start,
                       int* __restrict__ cursor, int* __restrict__ csr_eid) {
  int e = blockIdx.x * blockDim.x + threadIdx.x;
  if (e < N_EDGES) {
    int d = dst[e];
    int pos = atomicAdd(&cursor[d], 1);
    csr_eid[row_start[d] + pos] = e;
  }
}

__global__ void k_loop_attr(const float* __restrict__ edge_attr, const int* __restrict__ row_start,
                            const int* __restrict__ csr_eid, float* __restrict__ loop_attr) {
  int t = blockIdx.x * blockDim.x + threadIdx.x;
  if (t >= N_NODES * BOND) return;
  int i = t / BOND, k = t % BOND;
  int beg = row_start[i], end = row_start[i + 1];
  float s = 0.f;
  for (int p = beg; p < end; p++) s += edge_attr[(size_t)csr_eid[p] * BOND + k];
  int degv = end - beg;
  loop_attr[(size_t)i * BOND + k] = s / fmaxf((float)degv, 1.f);
}

// ---------------- build Bt: [L][4096][256] bf16 of [Wl|Wr]^T ----------------
__global__ __launch_bounds__(256) void k_build_bt(const float* __restrict__ Wl,
                                                  const float* __restrict__ Wr,
                                                  ushort_t* __restrict__ Bt) {
  int l = blockIdx.x >> 12;          // /4096
  int n = blockIdx.x & 4095;
  int k = threadIdx.x;               // 0..255
  const float* Wsrc = (n < HH) ? Wl : Wr;
  int nn = (n < HH) ? n : n - HH;
  float w = Wsrc[(size_t)l * HDIM * HH + (size_t)k * HH + nn];
  Bt[((size_t)l * 4096 + n) * 256 + k] = f2bf(w);
}

// ---------------- embedding: Linear -> LN -> ReLU, writes h + Abuf ----------------
__global__ __launch_bounds__(256) void k_embed(const float* __restrict__ x, const float* __restrict__ W,
                                               const float* __restrict__ b, const float* __restrict__ g,
                                               const float* __restrict__ beta, float* __restrict__ h,
                                               ushort_t* __restrict__ Abuf) {
  __shared__ float xs[ATOM];
  __shared__ float red[256];
  int i = blockIdx.x, j = threadIdx.x;
  if (j < ATOM) xs[j] = x[(size_t)i * ATOM + j];
  __syncthreads();
  float acc = b[j];
  for (int k = 0; k < ATOM; k++) acc += xs[k] * W[(size_t)k * HDIM + j];
  float mean = block_reduce_sum(acc, red) * (1.f / HDIM);
  float diff = acc - mean;
  float var = block_reduce_sum(diff * diff, red) * (1.f / HDIM);
  float vn = diff * rsqrtf(var + LN_EPS) * g[j] + beta[j];
  float r = fmaxf(vn, 0.f);
  h[(size_t)i * HDIM + j] = r;
  Abuf[(size_t)i * 256 + j] = f2bf(r);
}

// ---------------- MFMA GEMM: C[8064x4096] = A[Mx256] @ B[256x4096], bf16 in/out ----------------
__global__ __launch_bounds__(256) void k_gemm_mfma(const ushort_t* __restrict__ A,
                                                   const ushort_t* __restrict__ Bt,
                                                   ushort_t* __restrict__ C) {
  __shared__ char smem[128 * 136 * 2];              // Cs overlays As+Bs
  ushort_t* As = (ushort_t*)smem;                   // [128][32]
  ushort_t* Bs = (ushort_t*)(smem + 8192);          // [128][32]
  ushort_t* Cs = (ushort_t*)smem;                   // [128][136]
  const int tid = threadIdx.x;
  const int wave = tid >> 6, lane = tid & 63;
  const int bm = blockIdx.y * 128, bn = blockIdx.x * 128;
  const int wm = (wave >> 1) * 64, wn = (wave & 1) * 64;

  const int c0 = tid, c1 = tid + 256;
  const int ar0 = c0 >> 2, ap0 = (c0 & 3) * 8;
  const int ar1 = c1 >> 2, ap1 = (c1 & 3) * 8;
  const ushort_t* agA0 = A + (size_t)(bm + ar0) * 256 + ap0;
  const ushort_t* agA1 = A + (size_t)(bm + ar1) * 256 + ap1;
  const ushort_t* agB0 = Bt + (size_t)(bn + ar0) * 256 + ap0;
  const ushort_t* agB1 = Bt + (size_t)(bn + ar1) * 256 + ap1;
  ushort_t* alA0 = As + c0 * 8;
  ushort_t* alA1 = As + c1 * 8;
  ushort_t* alB0 = Bs + c0 * 8;
  ushort_t* alB1 = Bs + c1 * 8;

  floatx4 acc[4][4] = {};
  const int mrow = lane & 15;
  const int kq = (lane >> 4) * 8;

  for (int k0 = 0; k0 < 256; k0 += 32) {
    load_lds16(agA0 + k0, alA0);
    load_lds16(agA1 + k0, alA1);
    load_lds16(agB0 + k0, alB0);
    load_lds16(agB1 + k0, alB1);
    __syncthreads();
    short8 af[4], bfr[4];
#pragma unroll
    for (int mi = 0; mi < 4; mi++)
      af[mi] = *(const short8*)&As[(wm + mi * 16 + mrow) * 32 + kq];
#pragma unroll
    for (int ni = 0; ni < 4; ni++)
      bfr[ni] = *(const short8*)&Bs[(wn + ni * 16 + mrow) * 32 + kq];
#pragma unroll
    for (int mi = 0; mi < 4; mi++)
#pragma unroll
      for (int ni = 0; ni < 4; ni++)
        acc[mi][ni] = __builtin_amdgcn_mfma_f32_16x16x32_bf16(af[mi], bfr[ni], acc[mi][ni], 0, 0, 0);
    __syncthreads();
  }
  // stage bf16 C tile in LDS, then coalesced 16B global stores
  const int lr = (lane >> 4) * 4, lc = lane & 15;
#pragma unroll
  for (int mi = 0; mi < 4; mi++)
#pragma unroll
    for (int ni = 0; ni < 4; ni++)
#pragma unroll
      for (int r = 0; r < 4; r++)
        Cs[(wm + mi * 16 + lr + r) * 136 + wn + ni * 16 + lc] = f2bf(acc[mi][ni][r]);
  __syncthreads();
#pragma unroll
  for (int it = 0; it < 8; it++) {
    int idx = it * 256 + tid;
    int row = idx >> 4, chunk = idx & 15;
    int grow = bm + row;
    if (grow < N_NODES) {
      short8 v = *(const short8*)&Cs[row * 136 + chunk * 8];
      *(short8*)&C[(size_t)grow * 4096 + bn + chunk * 8] = v;
    }
  }
}

// ---------------- fused attention + head-mean + bias + residual + LN ----------------
__device__ __forceinline__ float edge_score(float x0, float x1, float x2, float x3,
                                            float r0, float r1, float r2, float r3,
                                            const float eav[BOND], const float wreg[BOND][4],
                                            float a0, float a1, float a2, float a3) {
  float e0 = 0.f, e1 = 0.f, e2 = 0.f, e3 = 0.f;
#pragma unroll
  for (int k = 0; k < BOND; k++) {
    e0 += eav[k] * wreg[k][0]; e1 += eav[k] * wreg[k][1];
    e2 += eav[k] * wreg[k][2]; e3 += eav[k] * wreg[k][3];
  }
  float f0 = x0 + r0 + e0; f0 = f0 > 0.f ? f0 : NEG * f0;
  float f1 = x1 + r1 + e1; f1 = f1 > 0.f ? f1 : NEG * f1;
  float f2 = x2 + r2 + e2; f2 = f2 > 0.f ? f2 : NEG * f2;
  float f3 = x3 + r3 + e3; f3 = f3 > 0.f ? f3 : NEG * f3;
  float sp = f0 * a0 + f1 * a1 + f2 * a2 + f3 * a3;
#pragma unroll
  for (int off = 32; off > 0; off >>= 1) sp += __shfl_xor(sp, off);
  return sp;
}

// block = 512 threads = 8 waves (one per head) handling 8 nodes; grid = 1000
__global__ __launch_bounds__(512) void k_attn(const ushort_t* __restrict__ xlr,
    const float* __restrict__ edge_attr, const float* __restrict__ loop_attr,
    const float* __restrict__ We, const float* __restrict__ att,
    const int* __restrict__ row_start, const int* __restrict__ csr_eid,
    const int* __restrict__ src, const float* __restrict__ bias,
    const float* __restrict__ lng, const float* __restrict__ lnb,
    float* __restrict__ h, ushort_t* __restrict__ Abuf) {
  __shared__ float sacc[HEADS][260];
  const int tid = threadIdx.x, hh = tid >> 6, lane = tid & 63;
  float wreg[BOND][4];
#pragma unroll
  for (int k = 0; k < BOND; k++) {
    float4 t = *(const float4*)&We[(size_t)k * HH + hh * HDIM + lane * 4];
    wreg[k][0] = t.x; wreg[k][1] = t.y; wreg[k][2] = t.z; wreg[k][3] = t.w;
  }
  float4 at4 = *(const float4*)&att[hh * HDIM + lane * 4];

  for (int ni = 0; ni < 8; ni++) {
    int i = blockIdx.x * 8 + ni;
    int beg = row_start[i], end = row_start[i + 1];
    float4 xr4 = ldbf4(&xlr[(size_t)i * 4096 + 2048 + hh * HDIM + lane * 4]);
    float4 xl4 = ldbf4(&xlr[(size_t)i * 4096 + hh * HDIM + lane * 4]);
    float eav[BOND];
#pragma unroll
    for (int k = 0; k < BOND; k++) eav[k] = loop_attr[(size_t)i * BOND + k];
    float s = edge_score(xl4.x, xl4.y, xl4.z, xl4.w, xr4.x, xr4.y, xr4.z, xr4.w,
                         eav, wreg, at4.x, at4.y, at4.z, at4.w);
    float m = s, l = 1.f;
    float o0 = xl4.x, o1 = xl4.y, o2 = xl4.z, o3 = xl4.w;
    for (int p = beg; p < end; p++) {
      int e = csr_eid[p];
      int sn = src[e];
#pragma unroll
      for (int k = 0; k < BOND; k++) eav[k] = edge_attr[(size_t)e * BOND + k];
      float4 x4 = ldbf4(&xlr[(size_t)sn * 4096 + hh * HDIM + lane * 4]);
      float s2 = edge_score(x4.x, x4.y, x4.z, x4.w, xr4.x, xr4.y, xr4.z, xr4.w,
                            eav, wreg, at4.x, at4.y, at4.z, at4.w);
      float mn = fmaxf(m, s2);
      float ca = __expf(m - mn), cb = __expf(s2 - mn);
      o0 = o0 * ca + x4.x * cb;
      o1 = o1 * ca + x4.y * cb;
      o2 = o2 * ca + x4.z * cb;
      o3 = o3 * ca + x4.w * cb;
      l = l * ca + cb;
      m = mn;
    }
    float inv = 1.f / l;
    *(float4*)&sacc[hh][lane * 4] = make_float4(o0 * inv, o1 * inv, o2 * inv, o3 * inv);
    __syncthreads();
    if (hh == 0) {
      // wave 0: head-mean + bias + residual + LN for node i (lane owns 4 dims)
      float v[4];
      float4 hres = *(const float4*)&h[(size_t)i * HDIM + lane * 4];
      float hr[4] = {hres.x, hres.y, hres.z, hres.w};
#pragma unroll
      for (int j = 0; j < 4; j++) {
        int d = lane * 4 + j;
        float sum = 0.f;
#pragma unroll
        for (int q = 0; q < HEADS; q++) sum += sacc[q][d];
        v[j] = sum * 0.125f + bias[d] + hr[j];
      }
      float tot = v[0] + v[1] + v[2] + v[3];
#pragma unroll
      for (int off = 32; off > 0; off >>= 1) tot += __shfl_xor(tot, off);
      float mean = tot * (1.f / HDIM);
      float df[4], vr = 0.f;
#pragma unroll
      for (int j = 0; j < 4; j++) { df[j] = v[j] - mean; vr += df[j] * df[j]; }
#pragma unroll
      for (int off = 32; off > 0; off >>= 1) vr += __shfl_xor(vr, off);
      float rstd = rsqrtf(vr * (1.f / HDIM) + LN_EPS);
      float4 g4 = *(const float4*)&lng[lane * 4];
      float4 b4 = *(const float4*)&lnb[lane * 4];
      float gg[4] = {g4.x, g4.y, g4.z, g4.w};
      float bb[4] = {b4.x, b4.y, b4.z, b4.w};
      float r[4];
      ushort4 hi;
#pragma unroll
      for (int j = 0; j < 4; j++) r[j] = df[j] * rstd * gg[j] + bb[j];
      hi.x = f2bf(r[0]); hi.y = f2bf(r[1]); hi.z = f2bf(r[2]); hi.w = f2bf(r[3]);
      *(float4*)&h[(size_t)i * HDIM + lane * 4] = make_float4(r[0], r[1], r[2], r[3]);
      *(ushort4*)&Abuf[(size_t)i * 256 + lane * 4] = hi;
    }
    __syncthreads();
  }
}

// ---------------- readout: gate MLP ----------------
__global__ __launch_bounds__(128) void k_gate(const float* __restrict__ h, const float* __restrict__ g1W,
                                              const float* __restrict__ g1b, const float* __restrict__ g2W,
                                              const float* __restrict__ g2b, float* __restrict__ gate) {
  __shared__ float red[128];
  int i = blockIdx.x, j = threadIdx.x;
  const float* hp = h + (size_t)i * HDIM;
  float acc = g1b[j];
  for (int k = 0; k < HDIM; k++) acc += hp[k] * g1W[(size_t)k * (HDIM / 2) + j];
  float r = fmaxf(acc, 0.f) * g2W[j];
  float tot = block_reduce_sum(r, red);
  if (j == 0) gate[i] = tot + g2b[0];
}

__global__ void k_gcount(const int* __restrict__ batch, int* __restrict__ gcnt) {
  int i = blockIdx.x * blockDim.x + threadIdx.x;
  if (i < N_NODES) atomicAdd(&gcnt[batch[i]], 1);
}

__global__ __launch_bounds__(256) void k_readout(const float* __restrict__ h, const float* __restrict__ gate,
                                                 const int* __restrict__ goff, float* __restrict__ out) {
  __shared__ float red[256];
  int b = blockIdx.x, t = threadIdx.x;
  int beg = goff[b], end = goff[b + 1];
  if (end <= beg) { out[(size_t)b * HDIM + t] = 0.f; return; }
  float lm = -3.4e38f;
  for (int i = beg + t; i < end; i += 256) lm = fmaxf(lm, gate[i]);
  float m = block_reduce_max(lm, red);
  float ls = 0.f;
  for (int i = beg + t; i < end; i += 256) ls += __expf(gate[i] - m);
  float s = block_reduce_sum(ls, red);
  float inv = 1.f / fmaxf(s, 1e-16f);
  float acc = 0.f;
  for (int i = beg; i < end; i++) acc += __expf(gate[i] - m) * h[(size_t)i * HDIM + t];
  out[(size_t)b * HDIM + t] = acc * inv;
}

// ---------------- launch ----------------
extern "C" void kernel_launch(void* const* d_in, const int* in_sizes, int n_in,
                              void* d_out, int out_size, void* d_ws, size_t ws_size,
                              hipStream_t stream) {
  const float* x         = (const float*)d_in[0];
  const float* edge_attr = (const float*)d_in[1];
  const float* emb_W     = (const float*)d_in[2];
  const float* emb_b     = (const float*)d_in[3];
  const float* emb_g     = (const float*)d_in[4];
  const float* emb_beta  = (const float*)d_in[5];
  const float* Wl        = (const float*)d_in[6];
  const float* Wr        = (const float*)d_in[7];
  const float* We        = (const float*)d_in[8];
  const float* att       = (const float*)d_in[9];
  const float* bias      = (const float*)d_in[10];
  const float* ln_g      = (const float*)d_in[11];
  const float* ln_b      = (const float*)d_in[12];
  const float* g1W       = (const float*)d_in[13];
  const float* g1b       = (const float*)d_in[14];
  const float* g2W       = (const float*)d_in[15];
  const float* g2b       = (const float*)d_in[16];
  const int*   edge_index= (const int*)d_in[17];
  const int*   batch     = (const int*)d_in[18];
  float* out = (float*)d_out;

  const int* src = edge_index;
  const int* dst = edge_index + N_EDGES;

  char* p = (char*)d_ws;
  auto alloc = [&](size_t bytes) -> void* {
    void* r = (void*)p;
    p += (bytes + 255) & ~(size_t)255;
    return r;
  };
  int*   deg       = (int*)alloc((size_t)N_NODES * 4);
  int*   row_start = (int*)alloc((size_t)(N_NODES + 1) * 4);
  int*   cursor    = (int*)alloc((size_t)N_NODES * 4);
  int*   csr_eid   = (int*)alloc((size_t)N_EDGES * 4);
  float* loop_attr = (float*)alloc((size_t)N_NODES * BOND * 4);
  float* h         = (float*)alloc((size_t)N_NODES * HDIM * 4);
  ushort_t* Abuf   = (ushort_t*)alloc((size_t)MPAD * 256 * 2);
  ushort_t* Bt     = (ushort_t*)alloc((size_t)NLAYERS * 4096 * 256 * 2);
  ushort_t* xlr    = (ushort_t*)alloc((size_t)N_NODES * 4096 * 2);
  float* gate      = (float*)alloc((size_t)N_NODES * 4);
  int*   gcnt      = (int*)alloc((size_t)NB * 4);
  int*   goff      = (int*)alloc((size_t)(NB + 1) * 4);

  hipMemsetAsync(deg, 0, (size_t)N_NODES * 4, stream);
  hipMemsetAsync(cursor, 0, (size_t)N_NODES * 4, stream);
  hipMemsetAsync(gcnt, 0, (size_t)NB * 4, stream);

  k_deg<<<(N_EDGES + 255) / 256, 256, 0, stream>>>(dst, deg);
  k_scan<<<1, 256, 0, stream>>>(deg, row_start, N_NODES);
  k_fill<<<(N_EDGES + 255) / 256, 256, 0, stream>>>(dst, row_start, cursor, csr_eid);
  k_loop_attr<<<(N_NODES * BOND + 255) / 256, 256, 0, stream>>>(edge_attr, row_start, csr_eid, loop_attr);
  k_build_bt<<<NLAYERS * 4096, 256, 0, stream>>>(Wl, Wr, Bt);
  k_embed<<<N_NODES, 256, 0, stream>>>(x, emb_W, emb_b, emb_g, emb_beta, h, Abuf);

  dim3 ggrid(4096 / 128, MPAD / 128);  // (32, 63)
  for (int l = 0; l < NLAYERS; l++) {
    const ushort_t* Bt_l = Bt + (size_t)l * 4096 * 256;
    const float* We_l  = We + (size_t)l * BOND * HH;
    const float* att_l = att + (size_t)l * HEADS * HDIM;
    k_gemm_mfma<<<ggrid, 256, 0, stream>>>(Abuf, Bt_l, xlr);
    k_attn<<<1000, 512, 0, stream>>>(xlr, edge_attr, loop_attr, We_l, att_l,
                                     row_start, csr_eid, src,
                                     bias + (size_t)l * HDIM, ln_g + (size_t)l * HDIM,
                                     ln_b + (size_t)l * HDIM, h, Abuf);
  }

  k_gate<<<N_NODES, 128, 0, stream>>>(h, g1W, g1b, g2W, g2b, gate);
  k_gcount<<<(N_NODES + 255) / 256, 256, 0, stream>>>(batch, gcnt);
  k_scan<<<1, 256, 0, stream>>>(gcnt, goff, NB);
  k_readout<<<NB, 256, 0, stream>>>(h, gate, goff, out);
}

// Round 4
// 876.031 us; speedup vs baseline: 3.1402x; 1.3749x over previous
//
#include <hip/hip_runtime.h>
#include <math.h>

#define N_NODES 8000
#define N_EDGES 24000
#define NB      256
#define ATOM    133
#define BOND    14
#define HDIM    256
#define HEADS   8
#define NLAYERS 5
#define NEG     0.2f
#define LN_EPS  1e-5f
#define HH      (HEADS * HDIM)   // 2048
#define MPAD    8064             // 63*128, padded rows for GEMM

typedef __attribute__((ext_vector_type(8))) short short8;
typedef __attribute__((ext_vector_type(4))) float floatx4;
typedef unsigned short ushort_t;

// ---------------- bf16 helpers (RNE) ----------------
__device__ __forceinline__ ushort_t f2bf(float f) {
  unsigned u = __float_as_uint(f);
  unsigned r = (u + 0x7fff + ((u >> 16) & 1)) >> 16;
  return (ushort_t)r;
}
__device__ __forceinline__ float bf2f(ushort_t h) {
  return __uint_as_float(((unsigned)h) << 16);
}
__device__ __forceinline__ float4 ldbf4(const ushort_t* p) {
  ushort4 u = *(const ushort4*)p;
  return make_float4(bf2f(u.x), bf2f(u.y), bf2f(u.z), bf2f(u.w));
}

// ---------------- async global->LDS 16B ----------------
__device__ __forceinline__ void load_lds16(const void* g, void* l) {
  __builtin_amdgcn_global_load_lds((const __attribute__((address_space(1))) unsigned int*)g,
                                   (__attribute__((address_space(3))) unsigned int*)l,
                                   16, 0, 0);
}

// ---------------- block reductions ----------------
__device__ __forceinline__ float block_reduce_sum(float v, float* red) {
  int t = threadIdx.x;
  red[t] = v; __syncthreads();
  for (int s = blockDim.x >> 1; s > 0; s >>= 1) {
    if (t < s) red[t] += red[t + s];
    __syncthreads();
  }
  float r = red[0]; __syncthreads();
  return r;
}
__device__ __forceinline__ float block_reduce_max(float v, float* red) {
  int t = threadIdx.x;
  red[t] = v; __syncthreads();
  for (int s = blockDim.x >> 1; s > 0; s >>= 1) {
    if (t < s) red[t] = fmaxf(red[t], red[t + s]);
    __syncthreads();
  }
  float r = red[0]; __syncthreads();
  return r;
}

// ---------------- CSR setup ----------------
__global__ void k_deg(const int* __restrict__ dst, int* __restrict__ deg) {
  int e = blockIdx.x * blockDim.x + threadIdx.x;
  if (e < N_EDGES) atomicAdd(&deg[dst[e]], 1);
}

__global__ void k_scan(const int* __restrict__ cnt, int* __restrict__ offs, int n) {
  __shared__ int sh[256];
  __shared__ int carry_s;
  int t = threadIdx.x;
  if (t == 0) carry_s = 0;
  __syncthreads();
  for (int base = 0; base < n; base += 256) {
    int i = base + t;
    int v = (i < n) ? cnt[i] : 0;
    sh[t] = v;
    __syncthreads();
    for (int off = 1; off < 256; off <<= 1) {
      int tmp = (t >= off) ? sh[t - off] : 0;
      __syncthreads();
      sh[t] += tmp;
      __syncthreads();
    }
    int carry = carry_s;
    if (i < n) offs[i] = carry + sh[t] - v;
    __syncthreads();
    if (t == 255) carry_s = carry + sh[255];
    __syncthreads();
  }
  if (t == 0) offs[n] = carry_s;
}

__global__ void k_fill(const int* __restrict__ dst, const int* __restrict__ row_start,
                       int* __restrict__ cursor, int* __restrict__ csr_eid) {
  int e = blockIdx.x * blockDim.x + threadIdx.x;
  if (e < N_EDGES) {
    int d = dst[e];
    int pos = atomicAdd(&cursor[d], 1);
    csr_eid[row_start[d] + pos] = e;
  }
}

__global__ void k_loop_attr(const float* __restrict__ edge_attr, const int* __restrict__ row_start,
                            const int* __restrict__ csr_eid, float* __restrict__ loop_attr) {
  int t = blockIdx.x * blockDim.x + threadIdx.x;
  if (t >= N_NODES * BOND) return;
  int i = t / BOND, k = t % BOND;
  int beg = row_start[i], end = row_start[i + 1];
  float s = 0.f;
  for (int p = beg; p < end; p++) s += edge_attr[(size_t)csr_eid[p] * BOND + k];
  int degv = end - beg;
  loop_attr[(size_t)i * BOND + k] = s / fmaxf((float)degv, 1.f);
}

// ---------------- build Bt: [L][4096][256] bf16 of [Wl|Wr]^T ----------------
__global__ __launch_bounds__(256) void k_build_bt(const float* __restrict__ Wl,
                                                  const float* __restrict__ Wr,
                                                  ushort_t* __restrict__ Bt) {
  int l = blockIdx.x >> 12;          // /4096
  int n = blockIdx.x & 4095;
  int k = threadIdx.x;               // 0..255
  const float* Wsrc = (n < HH) ? Wl : Wr;
  int nn = (n < HH) ? n : n - HH;
  float w = Wsrc[(size_t)l * HDIM * HH + (size_t)k * HH + nn];
  Bt[((size_t)l * 4096 + n) * 256 + k] = f2bf(w);
}

// ---------------- embedding: Linear -> LN -> ReLU, writes h + Abuf ----------------
__global__ __launch_bounds__(256) void k_embed(const float* __restrict__ x, const float* __restrict__ W,
                                               const float* __restrict__ b, const float* __restrict__ g,
                                               const float* __restrict__ beta, float* __restrict__ h,
                                               ushort_t* __restrict__ Abuf) {
  __shared__ float xs[ATOM];
  __shared__ float red[256];
  int i = blockIdx.x, j = threadIdx.x;
  if (j < ATOM) xs[j] = x[(size_t)i * ATOM + j];
  __syncthreads();
  float acc = b[j];
  for (int k = 0; k < ATOM; k++) acc += xs[k] * W[(size_t)k * HDIM + j];
  float mean = block_reduce_sum(acc, red) * (1.f / HDIM);
  float diff = acc - mean;
  float var = block_reduce_sum(diff * diff, red) * (1.f / HDIM);
  float vn = diff * rsqrtf(var + LN_EPS) * g[j] + beta[j];
  float r = fmaxf(vn, 0.f);
  h[(size_t)i * HDIM + j] = r;
  Abuf[(size_t)i * 256 + j] = f2bf(r);
}

// ---------------- MFMA GEMM: C[8064x4096] = A[Mx256] @ B[256x4096], bf16 in/out ----------------
__global__ __launch_bounds__(256) void k_gemm_mfma(const ushort_t* __restrict__ A,
                                                   const ushort_t* __restrict__ Bt,
                                                   ushort_t* __restrict__ C) {
  __shared__ char smem[128 * 136 * 2];              // Cs overlays As+Bs
  ushort_t* As = (ushort_t*)smem;                   // [128][32]
  ushort_t* Bs = (ushort_t*)(smem + 8192);          // [128][32]
  ushort_t* Cs = (ushort_t*)smem;                   // [128][136]
  const int tid = threadIdx.x;
  const int wave = tid >> 6, lane = tid & 63;
  const int bm = blockIdx.y * 128, bn = blockIdx.x * 128;
  const int wm = (wave >> 1) * 64, wn = (wave & 1) * 64;

  const int c0 = tid, c1 = tid + 256;
  const int ar0 = c0 >> 2, ap0 = (c0 & 3) * 8;
  const int ar1 = c1 >> 2, ap1 = (c1 & 3) * 8;
  const ushort_t* agA0 = A + (size_t)(bm + ar0) * 256 + ap0;
  const ushort_t* agA1 = A + (size_t)(bm + ar1) * 256 + ap1;
  const ushort_t* agB0 = Bt + (size_t)(bn + ar0) * 256 + ap0;
  const ushort_t* agB1 = Bt + (size_t)(bn + ar1) * 256 + ap1;
  ushort_t* alA0 = As + c0 * 8;
  ushort_t* alA1 = As + c1 * 8;
  ushort_t* alB0 = Bs + c0 * 8;
  ushort_t* alB1 = Bs + c1 * 8;

  floatx4 acc[4][4] = {};
  const int mrow = lane & 15;
  const int kq = (lane >> 4) * 8;

  for (int k0 = 0; k0 < 256; k0 += 32) {
    load_lds16(agA0 + k0, alA0);
    load_lds16(agA1 + k0, alA1);
    load_lds16(agB0 + k0, alB0);
    load_lds16(agB1 + k0, alB1);
    __syncthreads();
    short8 af[4], bfr[4];
#pragma unroll
    for (int mi = 0; mi < 4; mi++)
      af[mi] = *(const short8*)&As[(wm + mi * 16 + mrow) * 32 + kq];
#pragma unroll
    for (int ni = 0; ni < 4; ni++)
      bfr[ni] = *(const short8*)&Bs[(wn + ni * 16 + mrow) * 32 + kq];
#pragma unroll
    for (int mi = 0; mi < 4; mi++)
#pragma unroll
      for (int ni = 0; ni < 4; ni++)
        acc[mi][ni] = __builtin_amdgcn_mfma_f32_16x16x32_bf16(af[mi], bfr[ni], acc[mi][ni], 0, 0, 0);
    __syncthreads();
  }
  // stage bf16 C tile in LDS, then coalesced 16B global stores
  const int lr = (lane >> 4) * 4, lc = lane & 15;
#pragma unroll
  for (int mi = 0; mi < 4; mi++)
#pragma unroll
    for (int ni = 0; ni < 4; ni++)
#pragma unroll
      for (int r = 0; r < 4; r++)
        Cs[(wm + mi * 16 + lr + r) * 136 + wn + ni * 16 + lc] = f2bf(acc[mi][ni][r]);
  __syncthreads();
#pragma unroll
  for (int it = 0; it < 8; it++) {
    int idx = it * 256 + tid;
    int row = idx >> 4, chunk = idx & 15;
    int grow = bm + row;
    if (grow < N_NODES) {
      short8 v = *(const short8*)&Cs[row * 136 + chunk * 8];
      *(short8*)&C[(size_t)grow * 4096 + bn + chunk * 8] = v;
    }
  }
}

// ---------------- fused attention + head-mean + bias + residual + LN ----------------
__device__ __forceinline__ float edge_score(float x0, float x1, float x2, float x3,
                                            float r0, float r1, float r2, float r3,
                                            const float eav[BOND], const float wreg[BOND][4],
                                            float a0, float a1, float a2, float a3) {
  float e0 = 0.f, e1 = 0.f, e2 = 0.f, e3 = 0.f;
#pragma unroll
  for (int k = 0; k < BOND; k++) {
    e0 += eav[k] * wreg[k][0]; e1 += eav[k] * wreg[k][1];
    e2 += eav[k] * wreg[k][2]; e3 += eav[k] * wreg[k][3];
  }
  float f0 = x0 + r0 + e0; f0 = f0 > 0.f ? f0 : NEG * f0;
  float f1 = x1 + r1 + e1; f1 = f1 > 0.f ? f1 : NEG * f1;
  float f2 = x2 + r2 + e2; f2 = f2 > 0.f ? f2 : NEG * f2;
  float f3 = x3 + r3 + e3; f3 = f3 > 0.f ? f3 : NEG * f3;
  float sp = f0 * a0 + f1 * a1 + f2 * a2 + f3 * a3;
#pragma unroll
  for (int off = 32; off > 0; off >>= 1) sp += __shfl_xor(sp, off);
  return sp;
}

__device__ __forceinline__ void ld_eav(const float* p, float eav[BOND]) {
  // rows are 14 floats, 8-byte aligned -> 7 float2 loads
#pragma unroll
  for (int k = 0; k < 7; k++) {
    float2 t = *(const float2*)(p + 2 * k);
    eav[2 * k] = t.x; eav[2 * k + 1] = t.y;
  }
}

// block = 512 threads = 8 waves (one per head); 8 nodes per block; no per-node barriers.
// Per-head normalized outputs -> bf16 LDS; single barrier; wave w does LN for node w.
__global__ __launch_bounds__(512) void k_attn(const ushort_t* __restrict__ xlr,
    const float* __restrict__ edge_attr, const float* __restrict__ loop_attr,
    const float* __restrict__ We, const float* __restrict__ att,
    const int* __restrict__ row_start, const int* __restrict__ csr_eid,
    const int* __restrict__ src, const float* __restrict__ bias,
    const float* __restrict__ lng, const float* __restrict__ lnb,
    float* __restrict__ h, ushort_t* __restrict__ Abuf) {
  __shared__ ushort_t sacc[8][HEADS][264];
  const int tid = threadIdx.x, hh = tid >> 6, lane = tid & 63;
  float wreg[BOND][4];
#pragma unroll
  for (int k = 0; k < BOND; k++) {
    float4 t = *(const float4*)&We[(size_t)k * HH + hh * HDIM + lane * 4];
    wreg[k][0] = t.x; wreg[k][1] = t.y; wreg[k][2] = t.z; wreg[k][3] = t.w;
  }
  float4 at4 = *(const float4*)&att[hh * HDIM + lane * 4];
  const int node0 = blockIdx.x * 8;

  for (int ni = 0; ni < 8; ni++) {
    int i = node0 + ni;
    int beg = row_start[i], end = row_start[i + 1];
    float4 xr4 = ldbf4(&xlr[(size_t)i * 4096 + 2048 + hh * HDIM + lane * 4]);
    float4 xl4 = ldbf4(&xlr[(size_t)i * 4096 + hh * HDIM + lane * 4]);
    float eav[BOND];
    ld_eav(loop_attr + (size_t)i * BOND, eav);
    // prefetch first edge while self-score computes
    float4 px4;
    float peav[BOND];
    if (beg < end) {
      int e0 = csr_eid[beg];
      int sn0 = src[e0];
      px4 = ldbf4(&xlr[(size_t)sn0 * 4096 + hh * HDIM + lane * 4]);
      ld_eav(edge_attr + (size_t)e0 * BOND, peav);
    }
    float s = edge_score(xl4.x, xl4.y, xl4.z, xl4.w, xr4.x, xr4.y, xr4.z, xr4.w,
                         eav, wreg, at4.x, at4.y, at4.z, at4.w);
    float m = s, l = 1.f;
    float o0 = xl4.x, o1 = xl4.y, o2 = xl4.z, o3 = xl4.w;
    for (int p = beg; p < end; p++) {
      float4 x4 = px4;
      float ce[BOND];
#pragma unroll
      for (int k = 0; k < BOND; k++) ce[k] = peav[k];
      if (p + 1 < end) {   // prefetch next edge before dependent compute
        int e2 = csr_eid[p + 1];
        int sn2 = src[e2];
        px4 = ldbf4(&xlr[(size_t)sn2 * 4096 + hh * HDIM + lane * 4]);
        ld_eav(edge_attr + (size_t)e2 * BOND, peav);
      }
      float s2 = edge_score(x4.x, x4.y, x4.z, x4.w, xr4.x, xr4.y, xr4.z, xr4.w,
                            ce, wreg, at4.x, at4.y, at4.z, at4.w);
      float mn = fmaxf(m, s2);
      float ca = __expf(m - mn), cb = __expf(s2 - mn);
      o0 = o0 * ca + x4.x * cb;
      o1 = o1 * ca + x4.y * cb;
      o2 = o2 * ca + x4.z * cb;
      o3 = o3 * ca + x4.w * cb;
      l = l * ca + cb;
      m = mn;
    }
    float inv = 1.f / l;
    ushort4 st;
    st.x = f2bf(o0 * inv); st.y = f2bf(o1 * inv);
    st.z = f2bf(o2 * inv); st.w = f2bf(o3 * inv);
    *(ushort4*)&sacc[ni][hh][lane * 4] = st;
  }
  __syncthreads();
  // wave hh: head-mean + bias + residual + LN for node node0+hh
  {
    int i = node0 + hh;
    float4 hres = *(const float4*)&h[(size_t)i * HDIM + lane * 4];
    float hr[4] = {hres.x, hres.y, hres.z, hres.w};
    float v[4] = {0.f, 0.f, 0.f, 0.f};
#pragma unroll
    for (int q = 0; q < HEADS; q++) {
      ushort4 u = *(const ushort4*)&sacc[hh][q][lane * 4];
      v[0] += bf2f(u.x); v[1] += bf2f(u.y); v[2] += bf2f(u.z); v[3] += bf2f(u.w);
    }
    float4 bias4 = *(const float4*)&bias[lane * 4];
    float bi[4] = {bias4.x, bias4.y, bias4.z, bias4.w};
#pragma unroll
    for (int j = 0; j < 4; j++) v[j] = v[j] * 0.125f + bi[j] + hr[j];
    float tot = v[0] + v[1] + v[2] + v[3];
#pragma unroll
    for (int off = 32; off > 0; off >>= 1) tot += __shfl_xor(tot, off);
    float mean = tot * (1.f / HDIM);
    float df[4], vr = 0.f;
#pragma unroll
    for (int j = 0; j < 4; j++) { df[j] = v[j] - mean; vr += df[j] * df[j]; }
#pragma unroll
    for (int off = 32; off > 0; off >>= 1) vr += __shfl_xor(vr, off);
    float rstd = rsqrtf(vr * (1.f / HDIM) + LN_EPS);
    float4 g4 = *(const float4*)&lng[lane * 4];
    float4 b4 = *(const float4*)&lnb[lane * 4];
    float gg[4] = {g4.x, g4.y, g4.z, g4.w};
    float bb[4] = {b4.x, b4.y, b4.z, b4.w};
    float r[4];
    ushort4 hi;
#pragma unroll
    for (int j = 0; j < 4; j++) r[j] = df[j] * rstd * gg[j] + bb[j];
    hi.x = f2bf(r[0]); hi.y = f2bf(r[1]); hi.z = f2bf(r[2]); hi.w = f2bf(r[3]);
    *(float4*)&h[(size_t)i * HDIM + lane * 4] = make_float4(r[0], r[1], r[2], r[3]);
    *(ushort4*)&Abuf[(size_t)i * 256 + lane * 4] = hi;
  }
}

// ---------------- readout: gate MLP ----------------
__global__ __launch_bounds__(128) void k_gate(const float* __restrict__ h, const float* __restrict__ g1W,
                                              const float* __restrict__ g1b, const float* __restrict__ g2W,
                                              const float* __restrict__ g2b, float* __restrict__ gate) {
  __shared__ float red[128];
  int i = blockIdx.x, j = threadIdx.x;
  const float* hp = h + (size_t)i * HDIM;
  float acc = g1b[j];
  for (int k = 0; k < HDIM; k++) acc += hp[k] * g1W[(size_t)k * (HDIM / 2) + j];
  float r = fmaxf(acc, 0.f) * g2W[j];
  float tot = block_reduce_sum(r, red);
  if (j == 0) gate[i] = tot + g2b[0];
}

__global__ void k_gcount(const int* __restrict__ batch, int* __restrict__ gcnt) {
  int i = blockIdx.x * blockDim.x + threadIdx.x;
  if (i < N_NODES) atomicAdd(&gcnt[batch[i]], 1);
}

__global__ __launch_bounds__(256) void k_readout(const float* __restrict__ h, const float* __restrict__ gate,
                                                 const int* __restrict__ goff, float* __restrict__ out) {
  __shared__ float red[256];
  int b = blockIdx.x, t = threadIdx.x;
  int beg = goff[b], end = goff[b + 1];
  if (end <= beg) { out[(size_t)b * HDIM + t] = 0.f; return; }
  float lm = -3.4e38f;
  for (int i = beg + t; i < end; i += 256) lm = fmaxf(lm, gate[i]);
  float m = block_reduce_max(lm, red);
  float ls = 0.f;
  for (int i = beg + t; i < end; i += 256) ls += __expf(gate[i] - m);
  float s = block_reduce_sum(ls, red);
  float inv = 1.f / fmaxf(s, 1e-16f);
  float acc = 0.f;
  for (int i = beg; i < end; i++) acc += __expf(gate[i] - m) * h[(size_t)i * HDIM + t];
  out[(size_t)b * HDIM + t] = acc * inv;
}

// ---------------- launch ----------------
extern "C" void kernel_launch(void* const* d_in, const int* in_sizes, int n_in,
                              void* d_out, int out_size, void* d_ws, size_t ws_size,
                              hipStream_t stream) {
  const float* x         = (const float*)d_in[0];
  const float* edge_attr = (const float*)d_in[1];
  const float* emb_W     = (const float*)d_in[2];
  const float* emb_b     = (const float*)d_in[3];
  const float* emb_g     = (const float*)d_in[4];
  const float* emb_beta  = (const float*)d_in[5];
  const float* Wl        = (const float*)d_in[6];
  const float* Wr        = (const float*)d_in[7];
  const float* We        = (const float*)d_in[8];
  const float* att       = (const float*)d_in[9];
  const float* bias      = (const float*)d_in[10];
  const float* ln_g      = (const float*)d_in[11];
  const float* ln_b      = (const float*)d_in[12];
  const float* g1W       = (const float*)d_in[13];
  const float* g1b       = (const float*)d_in[14];
  const float* g2W       = (const float*)d_in[15];
  const float* g2b       = (const float*)d_in[16];
  const int*   edge_index= (const int*)d_in[17];
  const int*   batch     = (const int*)d_in[18];
  float* out = (float*)d_out;

  const int* src = edge_index;
  const int* dst = edge_index + N_EDGES;

  char* p = (char*)d_ws;
  auto alloc = [&](size_t bytes) -> void* {
    void* r = (void*)p;
    p += (bytes + 255) & ~(size_t)255;
    return r;
  };
  int*   deg       = (int*)alloc((size_t)N_NODES * 4);
  int*   row_start = (int*)alloc((size_t)(N_NODES + 1) * 4);
  int*   cursor    = (int*)alloc((size_t)N_NODES * 4);
  int*   csr_eid   = (int*)alloc((size_t)N_EDGES * 4);
  float* loop_attr = (float*)alloc((size_t)N_NODES * BOND * 4);
  float* h         = (float*)alloc((size_t)N_NODES * HDIM * 4);
  ushort_t* Abuf   = (ushort_t*)alloc((size_t)MPAD * 256 * 2);
  ushort_t* Bt     = (ushort_t*)alloc((size_t)NLAYERS * 4096 * 256 * 2);
  ushort_t* xlr    = (ushort_t*)alloc((size_t)N_NODES * 4096 * 2);
  float* gate      = (float*)alloc((size_t)N_NODES * 4);
  int*   gcnt      = (int*)alloc((size_t)NB * 4);
  int*   goff      = (int*)alloc((size_t)(NB + 1) * 4);

  hipMemsetAsync(deg, 0, (size_t)N_NODES * 4, stream);
  hipMemsetAsync(cursor, 0, (size_t)N_NODES * 4, stream);
  hipMemsetAsync(gcnt, 0, (size_t)NB * 4, stream);

  k_deg<<<(N_EDGES + 255) / 256, 256, 0, stream>>>(dst, deg);
  k_scan<<<1, 256, 0, stream>>>(deg, row_start, N_NODES);
  k_fill<<<(N_EDGES + 255) / 256, 256, 0, stream>>>(dst, row_start, cursor, csr_eid);
  k_loop_attr<<<(N_NODES * BOND + 255) / 256, 256, 0, stream>>>(edge_attr, row_start, csr_eid, loop_attr);
  k_build_bt<<<NLAYERS * 4096, 256, 0, stream>>>(Wl, Wr, Bt);
  k_embed<<<N_NODES, 256, 0, stream>>>(x, emb_W, emb_b, emb_g, emb_beta, h, Abuf);

  dim3 ggrid(4096 / 128, MPAD / 128);  // (32, 63)
  for (int l = 0; l < NLAYERS; l++) {
    const ushort_t* Bt_l = Bt + (size_t)l * 4096 * 256;
    const float* We_l  = We + (size_t)l * BOND * HH;
    const float* att_l = att + (size_t)l * HEADS * HDIM;
    k_gemm_mfma<<<ggrid, 256, 0, stream>>>(Abuf, Bt_l, xlr);
    k_attn<<<1000, 512, 0, stream>>>(xlr, edge_attr, loop_attr, We_l, att_l,
                                     row_start, csr_eid, src,
                                     bias + (size_t)l * HDIM, ln_g + (size_t)l * HDIM,
                                     ln_b + (size_t)l * HDIM, h, Abuf);
  }

  k_gate<<<N_NODES, 128, 0, stream>>>(h, g1W, g1b, g2W, g2b, gate);
  k_gcount<<<(N_NODES + 255) / 256, 256, 0, stream>>>(batch, gcnt);
  k_scan<<<1, 256, 0, stream>>>(gcnt, goff, NB);
  k_readout<<<NB, 256, 0, stream>>>(h, gate, goff, out);
}

// Round 5
// 849.529 us; speedup vs baseline: 3.2382x; 1.0312x over previous
//
#include <hip/hip_runtime.h>
#include <math.h>

#define N_NODES 8000
#define N_EDGES 24000
#define NB      256
#define ATOM    133
#define BOND    14
#define HDIM    256
#define HEADS   8
#define NLAYERS 5
#define NEG     0.2f
#define LN_EPS  1e-5f
#define HH      (HEADS * HDIM)   // 2048
#define MPAD    8064             // 63*128, padded rows for GEMM

typedef __attribute__((ext_vector_type(8))) short short8;
typedef __attribute__((ext_vector_type(4))) float floatx4;
typedef unsigned short ushort_t;

// ---------------- bf16 helpers (RNE) ----------------
__device__ __forceinline__ ushort_t f2bf(float f) {
  unsigned u = __float_as_uint(f);
  unsigned r = (u + 0x7fff + ((u >> 16) & 1)) >> 16;
  return (ushort_t)r;
}
__device__ __forceinline__ float bf2f(ushort_t h) {
  return __uint_as_float(((unsigned)h) << 16);
}
__device__ __forceinline__ float4 ldbf4(const ushort_t* p) {
  ushort4 u = *(const ushort4*)p;
  return make_float4(bf2f(u.x), bf2f(u.y), bf2f(u.z), bf2f(u.w));
}

// ---------------- async global->LDS 16B ----------------
__device__ __forceinline__ void load_lds16(const void* g, void* l) {
  __builtin_amdgcn_global_load_lds((const __attribute__((address_space(1))) unsigned int*)g,
                                   (__attribute__((address_space(3))) unsigned int*)l,
                                   16, 0, 0);
}

// ---------------- block reductions ----------------
__device__ __forceinline__ float block_reduce_sum(float v, float* red) {
  int t = threadIdx.x;
  red[t] = v; __syncthreads();
  for (int s = blockDim.x >> 1; s > 0; s >>= 1) {
    if (t < s) red[t] += red[t + s];
    __syncthreads();
  }
  float r = red[0]; __syncthreads();
  return r;
}
__device__ __forceinline__ float block_reduce_max(float v, float* red) {
  int t = threadIdx.x;
  red[t] = v; __syncthreads();
  for (int s = blockDim.x >> 1; s > 0; s >>= 1) {
    if (t < s) red[t] = fmaxf(red[t], red[t + s]);
    __syncthreads();
  }
  float r = red[0]; __syncthreads();
  return r;
}

// ---------------- CSR setup ----------------
__global__ void k_deg(const int* __restrict__ dst, int* __restrict__ deg) {
  int e = blockIdx.x * blockDim.x + threadIdx.x;
  if (e < N_EDGES) atomicAdd(&deg[dst[e]], 1);
}

// single-block exclusive scan, shfl wave-scan version
__global__ void k_scan(const int* __restrict__ cnt, int* __restrict__ offs, int n) {
  __shared__ int wsum[8];
  __shared__ int carry_s;
  int t = threadIdx.x, w = t >> 6, lane = t & 63;
  if (t == 0) carry_s = 0;
  __syncthreads();
  for (int base = 0; base < n; base += 256) {
    int i = base + t;
    int v = (i < n) ? cnt[i] : 0;
    int x = v;
#pragma unroll
    for (int off = 1; off < 64; off <<= 1) {
      int u = __shfl_up(x, off);
      if (lane >= off) x += u;
    }
    if (lane == 63) wsum[w] = x;
    __syncthreads();
    int wpre = 0;
    for (int q = 0; q < w; q++) wpre += wsum[q];
    int carry = carry_s;
    if (i < n) offs[i] = carry + wpre + x - v;
    __syncthreads();
    if (t == 255) carry_s = carry + wpre + x;
    __syncthreads();
  }
  if (t == 0) offs[n] = carry_s;
}

__global__ void k_fill(const int* __restrict__ dst, const int* __restrict__ row_start,
                       int* __restrict__ cursor, int* __restrict__ csr_eid) {
  int e = blockIdx.x * blockDim.x + threadIdx.x;
  if (e < N_EDGES) {
    int d = dst[e];
    int pos = atomicAdd(&cursor[d], 1);
    csr_eid[row_start[d] + pos] = e;
  }
}

__global__ void k_loop_attr(const float* __restrict__ edge_attr, const int* __restrict__ row_start,
                            const int* __restrict__ csr_eid, float* __restrict__ loop_attr) {
  int t = blockIdx.x * blockDim.x + threadIdx.x;
  if (t >= N_NODES * BOND) return;
  int i = t / BOND, k = t % BOND;
  int beg = row_start[i], end = row_start[i + 1];
  float s = 0.f;
  for (int p = beg; p < end; p++) s += edge_attr[(size_t)csr_eid[p] * BOND + k];
  int degv = end - beg;
  loop_attr[(size_t)i * BOND + k] = s / fmaxf((float)degv, 1.f);
}

// ---------------- build Bt: [L][4096][256] bf16 of [Wl|Wr]^T ----------------
__global__ __launch_bounds__(256) void k_build_bt(const float* __restrict__ Wl,
                                                  const float* __restrict__ Wr,
                                                  ushort_t* __restrict__ Bt) {
  int l = blockIdx.x >> 12;          // /4096
  int n = blockIdx.x & 4095;
  int k = threadIdx.x;               // 0..255
  const float* Wsrc = (n < HH) ? Wl : Wr;
  int nn = (n < HH) ? n : n - HH;
  float w = Wsrc[(size_t)l * HDIM * HH + (size_t)k * HH + nn];
  Bt[((size_t)l * 4096 + n) * 256 + k] = f2bf(w);
}

// ---------------- embedding: Linear -> LN -> ReLU, writes h + Abuf ----------------
__global__ __launch_bounds__(256) void k_embed(const float* __restrict__ x, const float* __restrict__ W,
                                               const float* __restrict__ b, const float* __restrict__ g,
                                               const float* __restrict__ beta, float* __restrict__ h,
                                               ushort_t* __restrict__ Abuf) {
  __shared__ float xs[ATOM];
  __shared__ float red[256];
  int i = blockIdx.x, j = threadIdx.x;
  if (j < ATOM) xs[j] = x[(size_t)i * ATOM + j];
  __syncthreads();
  float acc = b[j];
  for (int k = 0; k < ATOM; k++) acc += xs[k] * W[(size_t)k * HDIM + j];
  float mean = block_reduce_sum(acc, red) * (1.f / HDIM);
  float diff = acc - mean;
  float var = block_reduce_sum(diff * diff, red) * (1.f / HDIM);
  float vn = diff * rsqrtf(var + LN_EPS) * g[j] + beta[j];
  float r = fmaxf(vn, 0.f);
  h[(size_t)i * HDIM + j] = r;
  Abuf[(size_t)i * 256 + j] = f2bf(r);
}

// ---------------- MFMA GEMM: C[8064x4096] = A[Mx256] @ B[256x4096], bf16 in/out ----------------
// BK=64: 4 K-stages, 32 MFMA per stage between barriers.
__global__ __launch_bounds__(256) void k_gemm_mfma(const ushort_t* __restrict__ A,
                                                   const ushort_t* __restrict__ Bt,
                                                   ushort_t* __restrict__ C) {
  __shared__ char smem[34816];                      // max(As+Bs = 32768, Cs = 34816)
  ushort_t* As = (ushort_t*)smem;                   // [128][64]
  ushort_t* Bs = (ushort_t*)(smem + 16384);         // [128][64]
  ushort_t* Cs = (ushort_t*)smem;                   // [128][136] (overlay)
  const int tid = threadIdx.x;
  const int wave = tid >> 6, lane = tid & 63;
  const int bm = blockIdx.y * 128, bn = blockIdx.x * 128;
  const int wm = (wave >> 1) * 64, wn = (wave & 1) * 64;

  // staging: chunk c = j*256+tid (0..1023); row=c>>3, col=(c&7)*8; lds off = c*16B
  const ushort_t* agA[4];
  const ushort_t* agB[4];
  ushort_t* alA[4];
  ushort_t* alB[4];
#pragma unroll
  for (int j = 0; j < 4; j++) {
    int c = j * 256 + tid;
    int row = c >> 3, col = (c & 7) * 8;
    agA[j] = A  + (size_t)(bm + row) * 256 + col;
    agB[j] = Bt + (size_t)(bn + row) * 256 + col;
    alA[j] = As + c * 8;
    alB[j] = Bs + c * 8;
  }

  floatx4 acc[4][4] = {};
  const int mrow = lane & 15;
  const int kq = (lane >> 4) * 8;

  for (int k0 = 0; k0 < 256; k0 += 64) {
#pragma unroll
    for (int j = 0; j < 4; j++) load_lds16(agA[j] + k0, alA[j]);
#pragma unroll
    for (int j = 0; j < 4; j++) load_lds16(agB[j] + k0, alB[j]);
    __syncthreads();
#pragma unroll
    for (int half = 0; half < 2; half++) {
      const int kk = half * 32 + kq;
      short8 af[4], bfr[4];
#pragma unroll
      for (int mi = 0; mi < 4; mi++)
        af[mi] = *(const short8*)&As[(wm + mi * 16 + mrow) * 64 + kk];
#pragma unroll
      for (int ni = 0; ni < 4; ni++)
        bfr[ni] = *(const short8*)&Bs[(wn + ni * 16 + mrow) * 64 + kk];
#pragma unroll
      for (int mi = 0; mi < 4; mi++)
#pragma unroll
        for (int ni = 0; ni < 4; ni++)
          acc[mi][ni] = __builtin_amdgcn_mfma_f32_16x16x32_bf16(af[mi], bfr[ni], acc[mi][ni], 0, 0, 0);
    }
    __syncthreads();
  }
  // stage bf16 C tile in LDS, then coalesced 16B global stores
  const int lr = (lane >> 4) * 4, lc = lane & 15;
#pragma unroll
  for (int mi = 0; mi < 4; mi++)
#pragma unroll
    for (int ni = 0; ni < 4; ni++)
#pragma unroll
      for (int r = 0; r < 4; r++)
        Cs[(wm + mi * 16 + lr + r) * 136 + wn + ni * 16 + lc] = f2bf(acc[mi][ni][r]);
  __syncthreads();
#pragma unroll
  for (int it = 0; it < 8; it++) {
    int idx = it * 256 + tid;
    int row = idx >> 4, chunk = idx & 15;
    int grow = bm + row;
    if (grow < N_NODES) {
      short8 v = *(const short8*)&Cs[row * 136 + chunk * 8];
      *(short8*)&C[(size_t)grow * 4096 + bn + chunk * 8] = v;
    }
  }
}

// ---------------- fused attention + head-mean + bias + residual + LN ----------------
__device__ __forceinline__ float edge_score(float x0, float x1, float x2, float x3,
                                            float r0, float r1, float r2, float r3,
                                            const float eav[BOND], const float wreg[BOND][4],
                                            float a0, float a1, float a2, float a3) {
  float e0 = 0.f, e1 = 0.f, e2 = 0.f, e3 = 0.f;
#pragma unroll
  for (int k = 0; k < BOND; k++) {
    e0 += eav[k] * wreg[k][0]; e1 += eav[k] * wreg[k][1];
    e2 += eav[k] * wreg[k][2]; e3 += eav[k] * wreg[k][3];
  }
  float f0 = x0 + r0 + e0; f0 = f0 > 0.f ? f0 : NEG * f0;
  float f1 = x1 + r1 + e1; f1 = f1 > 0.f ? f1 : NEG * f1;
  float f2 = x2 + r2 + e2; f2 = f2 > 0.f ? f2 : NEG * f2;
  float f3 = x3 + r3 + e3; f3 = f3 > 0.f ? f3 : NEG * f3;
  float sp = f0 * a0 + f1 * a1 + f2 * a2 + f3 * a3;
#pragma unroll
  for (int off = 32; off > 0; off >>= 1) sp += __shfl_xor(sp, off);
  return sp;
}

__device__ __forceinline__ void ld_eav(const float* p, float eav[BOND]) {
#pragma unroll
  for (int k = 0; k < 7; k++) {
    float2 t = *(const float2*)(p + 2 * k);
    eav[2 * k] = t.x; eav[2 * k + 1] = t.y;
  }
}

// block = 512 threads = 8 waves (one per head); 2 nodes per block; grid = 4000.
// Per-head normalized outputs -> bf16 LDS; single barrier; waves 0-1 do LN.
__global__ __launch_bounds__(512) void k_attn(const ushort_t* __restrict__ xlr,
    const float* __restrict__ edge_attr, const float* __restrict__ loop_attr,
    const float* __restrict__ We, const float* __restrict__ att,
    const int* __restrict__ row_start, const int* __restrict__ csr_eid,
    const int* __restrict__ src, const float* __restrict__ bias,
    const float* __restrict__ lng, const float* __restrict__ lnb,
    float* __restrict__ h, ushort_t* __restrict__ Abuf) {
  __shared__ ushort_t sacc[2][HEADS][264];
  const int tid = threadIdx.x, hh = tid >> 6, lane = tid & 63;
  float wreg[BOND][4];
#pragma unroll
  for (int k = 0; k < BOND; k++) {
    float4 t = *(const float4*)&We[(size_t)k * HH + hh * HDIM + lane * 4];
    wreg[k][0] = t.x; wreg[k][1] = t.y; wreg[k][2] = t.z; wreg[k][3] = t.w;
  }
  float4 at4 = *(const float4*)&att[hh * HDIM + lane * 4];
  const int node0 = blockIdx.x * 2;

#pragma unroll
  for (int ni = 0; ni < 2; ni++) {
    int i = node0 + ni;
    int beg = row_start[i], end = row_start[i + 1];
    float4 xr4 = ldbf4(&xlr[(size_t)i * 4096 + 2048 + hh * HDIM + lane * 4]);
    float4 xl4 = ldbf4(&xlr[(size_t)i * 4096 + hh * HDIM + lane * 4]);
    float eav[BOND];
    ld_eav(loop_attr + (size_t)i * BOND, eav);
    float4 px4;
    float peav[BOND];
    if (beg < end) {
      int e0 = csr_eid[beg];
      int sn0 = src[e0];
      px4 = ldbf4(&xlr[(size_t)sn0 * 4096 + hh * HDIM + lane * 4]);
      ld_eav(edge_attr + (size_t)e0 * BOND, peav);
    }
    float s = edge_score(xl4.x, xl4.y, xl4.z, xl4.w, xr4.x, xr4.y, xr4.z, xr4.w,
                         eav, wreg, at4.x, at4.y, at4.z, at4.w);
    float m = s, l = 1.f;
    float o0 = xl4.x, o1 = xl4.y, o2 = xl4.z, o3 = xl4.w;
    for (int p = beg; p < end; p++) {
      float4 x4 = px4;
      float ce[BOND];
#pragma unroll
      for (int k = 0; k < BOND; k++) ce[k] = peav[k];
      if (p + 1 < end) {
        int e2 = csr_eid[p + 1];
        int sn2 = src[e2];
        px4 = ldbf4(&xlr[(size_t)sn2 * 4096 + hh * HDIM + lane * 4]);
        ld_eav(edge_attr + (size_t)e2 * BOND, peav);
      }
      float s2 = edge_score(x4.x, x4.y, x4.z, x4.w, xr4.x, xr4.y, xr4.z, xr4.w,
                            ce, wreg, at4.x, at4.y, at4.z, at4.w);
      float mn = fmaxf(m, s2);
      float ca = __expf(m - mn), cb = __expf(s2 - mn);
      o0 = o0 * ca + x4.x * cb;
      o1 = o1 * ca + x4.y * cb;
      o2 = o2 * ca + x4.z * cb;
      o3 = o3 * ca + x4.w * cb;
      l = l * ca + cb;
      m = mn;
    }
    float inv = 1.f / l;
    ushort4 st;
    st.x = f2bf(o0 * inv); st.y = f2bf(o1 * inv);
    st.z = f2bf(o2 * inv); st.w = f2bf(o3 * inv);
    *(ushort4*)&sacc[ni][hh][lane * 4] = st;
  }
  __syncthreads();
  if (hh < 2) {
    int i = node0 + hh;
    float4 hres = *(const float4*)&h[(size_t)i * HDIM + lane * 4];
    float hr[4] = {hres.x, hres.y, hres.z, hres.w};
    float v[4] = {0.f, 0.f, 0.f, 0.f};
#pragma unroll
    for (int q = 0; q < HEADS; q++) {
      ushort4 u = *(const ushort4*)&sacc[hh][q][lane * 4];
      v[0] += bf2f(u.x); v[1] += bf2f(u.y); v[2] += bf2f(u.z); v[3] += bf2f(u.w);
    }
    float4 bias4 = *(const float4*)&bias[lane * 4];
    float bi[4] = {bias4.x, bias4.y, bias4.z, bias4.w};
#pragma unroll
    for (int j = 0; j < 4; j++) v[j] = v[j] * 0.125f + bi[j] + hr[j];
    float tot = v[0] + v[1] + v[2] + v[3];
#pragma unroll
    for (int off = 32; off > 0; off >>= 1) tot += __shfl_xor(tot, off);
    float mean = tot * (1.f / HDIM);
    float df[4], vr = 0.f;
#pragma unroll
    for (int j = 0; j < 4; j++) { df[j] = v[j] - mean; vr += df[j] * df[j]; }
#pragma unroll
    for (int off = 32; off > 0; off >>= 1) vr += __shfl_xor(vr, off);
    float rstd = rsqrtf(vr * (1.f / HDIM) + LN_EPS);
    float4 g4 = *(const float4*)&lng[lane * 4];
    float4 b4 = *(const float4*)&lnb[lane * 4];
    float gg[4] = {g4.x, g4.y, g4.z, g4.w};
    float bb[4] = {b4.x, b4.y, b4.z, b4.w};
    float r[4];
    ushort4 hi;
#pragma unroll
    for (int j = 0; j < 4; j++) r[j] = df[j] * rstd * gg[j] + bb[j];
    hi.x = f2bf(r[0]); hi.y = f2bf(r[1]); hi.z = f2bf(r[2]); hi.w = f2bf(r[3]);
    *(float4*)&h[(size_t)i * HDIM + lane * 4] = make_float4(r[0], r[1], r[2], r[3]);
    *(ushort4*)&Abuf[(size_t)i * 256 + lane * 4] = hi;
  }
}

// ---------------- readout: gate MLP, 4 nodes per block ----------------
__global__ __launch_bounds__(128) void k_gate(const float* __restrict__ h, const float* __restrict__ g1W,
                                              const float* __restrict__ g1b, const float* __restrict__ g2W,
                                              const float* __restrict__ g2b, float* __restrict__ gate) {
  __shared__ float hs[4][HDIM];
  __shared__ float red[4][132];
  const int j = threadIdx.x;           // 0..127 (gate hidden dim)
  const int i0 = blockIdx.x * 4;
#pragma unroll
  for (int it = 0; it < 2; it++) {
    int c = it * 128 + j;              // 0..255 float4 chunks
    int node = c >> 6, off = (c & 63) * 4;
    *(float4*)&hs[node][off] = *(const float4*)&h[(size_t)(i0 + node) * HDIM + off];
  }
  __syncthreads();
  float acc[4];
  float b = g1b[j];
#pragma unroll
  for (int n = 0; n < 4; n++) acc[n] = b;
  for (int k = 0; k < HDIM; k++) {
    float w = g1W[(size_t)k * (HDIM / 2) + j];
#pragma unroll
    for (int n = 0; n < 4; n++) acc[n] += hs[n][k] * w;
  }
  float w2 = g2W[j];
#pragma unroll
  for (int n = 0; n < 4; n++) red[n][j] = fmaxf(acc[n], 0.f) * w2;
  __syncthreads();
  // thread j: node n = j>>5, sub-lane l2 = j&31 reduces 128 entries
  int n = j >> 5, l2 = j & 31;
  float s = red[n][l2] + red[n][l2 + 32] + red[n][l2 + 64] + red[n][l2 + 96];
#pragma unroll
  for (int off = 16; off > 0; off >>= 1) s += __shfl_xor(s, off, 32);
  if (l2 == 0) gate[i0 + n] = s + g2b[0];
}

__global__ void k_gcount(const int* __restrict__ batch, int* __restrict__ gcnt) {
  int i = blockIdx.x * blockDim.x + threadIdx.x;
  if (i < N_NODES) atomicAdd(&gcnt[batch[i]], 1);
}

__global__ __launch_bounds__(256) void k_readout(const float* __restrict__ h, const float* __restrict__ gate,
                                                 const int* __restrict__ goff, float* __restrict__ out) {
  __shared__ float red[256];
  int b = blockIdx.x, t = threadIdx.x;
  int beg = goff[b], end = goff[b + 1];
  if (end <= beg) { out[(size_t)b * HDIM + t] = 0.f; return; }
  float lm = -3.4e38f;
  for (int i = beg + t; i < end; i += 256) lm = fmaxf(lm, gate[i]);
  float m = block_reduce_max(lm, red);
  float ls = 0.f;
  for (int i = beg + t; i < end; i += 256) ls += __expf(gate[i] - m);
  float s = block_reduce_sum(ls, red);
  float inv = 1.f / fmaxf(s, 1e-16f);
  float acc = 0.f;
  for (int i = beg; i < end; i++) acc += __expf(gate[i] - m) * h[(size_t)i * HDIM + t];
  out[(size_t)b * HDIM + t] = acc * inv;
}

// ---------------- launch ----------------
extern "C" void kernel_launch(void* const* d_in, const int* in_sizes, int n_in,
                              void* d_out, int out_size, void* d_ws, size_t ws_size,
                              hipStream_t stream) {
  const float* x         = (const float*)d_in[0];
  const float* edge_attr = (const float*)d_in[1];
  const float* emb_W     = (const float*)d_in[2];
  const float* emb_b     = (const float*)d_in[3];
  const float* emb_g     = (const float*)d_in[4];
  const float* emb_beta  = (const float*)d_in[5];
  const float* Wl        = (const float*)d_in[6];
  const float* Wr        = (const float*)d_in[7];
  const float* We        = (const float*)d_in[8];
  const float* att       = (const float*)d_in[9];
  const float* bias      = (const float*)d_in[10];
  const float* ln_g      = (const float*)d_in[11];
  const float* ln_b      = (const float*)d_in[12];
  const float* g1W       = (const float*)d_in[13];
  const float* g1b       = (const float*)d_in[14];
  const float* g2W       = (const float*)d_in[15];
  const float* g2b       = (const float*)d_in[16];
  const int*   edge_index= (const int*)d_in[17];
  const int*   batch     = (const int*)d_in[18];
  float* out = (float*)d_out;

  const int* src = edge_index;
  const int* dst = edge_index + N_EDGES;

  char* p = (char*)d_ws;
  auto alloc = [&](size_t bytes) -> void* {
    void* r = (void*)p;
    p += (bytes + 255) & ~(size_t)255;
    return r;
  };
  int*   deg       = (int*)alloc((size_t)N_NODES * 4);
  int*   row_start = (int*)alloc((size_t)(N_NODES + 1) * 4);
  int*   cursor    = (int*)alloc((size_t)N_NODES * 4);
  int*   csr_eid   = (int*)alloc((size_t)N_EDGES * 4);
  float* loop_attr = (float*)alloc((size_t)N_NODES * BOND * 4);
  float* h         = (float*)alloc((size_t)N_NODES * HDIM * 4);
  ushort_t* Abuf   = (ushort_t*)alloc((size_t)MPAD * 256 * 2);
  ushort_t* Bt     = (ushort_t*)alloc((size_t)NLAYERS * 4096 * 256 * 2);
  ushort_t* xlr    = (ushort_t*)alloc((size_t)N_NODES * 4096 * 2);
  float* gate      = (float*)alloc((size_t)N_NODES * 4);
  int*   gcnt      = (int*)alloc((size_t)NB * 4);
  int*   goff      = (int*)alloc((size_t)(NB + 1) * 4);

  hipMemsetAsync(deg, 0, (size_t)N_NODES * 4, stream);
  hipMemsetAsync(cursor, 0, (size_t)N_NODES * 4, stream);
  hipMemsetAsync(gcnt, 0, (size_t)NB * 4, stream);

  k_deg<<<(N_EDGES + 255) / 256, 256, 0, stream>>>(dst, deg);
  k_scan<<<1, 256, 0, stream>>>(deg, row_start, N_NODES);
  k_fill<<<(N_EDGES + 255) / 256, 256, 0, stream>>>(dst, row_start, cursor, csr_eid);
  k_loop_attr<<<(N_NODES * BOND + 255) / 256, 256, 0, stream>>>(edge_attr, row_start, csr_eid, loop_attr);
  k_build_bt<<<NLAYERS * 4096, 256, 0, stream>>>(Wl, Wr, Bt);
  k_embed<<<N_NODES, 256, 0, stream>>>(x, emb_W, emb_b, emb_g, emb_beta, h, Abuf);

  dim3 ggrid(4096 / 128, MPAD / 128);  // (32, 63)
  for (int l = 0; l < NLAYERS; l++) {
    const ushort_t* Bt_l = Bt + (size_t)l * 4096 * 256;
    const float* We_l  = We + (size_t)l * BOND * HH;
    const float* att_l = att + (size_t)l * HEADS * HDIM;
    k_gemm_mfma<<<ggrid, 256, 0, stream>>>(Abuf, Bt_l, xlr);
    k_attn<<<4000, 512, 0, stream>>>(xlr, edge_attr, loop_attr, We_l, att_l,
                                     row_start, csr_eid, src,
                                     bias + (size_t)l * HDIM, ln_g + (size_t)l * HDIM,
                                     ln_b + (size_t)l * HDIM, h, Abuf);
  }

  k_gate<<<N_NODES / 4, 128, 0, stream>>>(h, g1W, g1b, g2W, g2b, gate);
  k_gcount<<<(N_NODES + 255) / 256, 256, 0, stream>>>(batch, gcnt);
  k_scan<<<1, 256, 0, stream>>>(gcnt, goff, NB);
  k_readout<<<NB, 256, 0, stream>>>(h, gate, goff, out);
}